// Round 6
// baseline (283.342 us; speedup 1.0000x reference)
//
#include <hip/hip_runtime.h>
#include <hip/hip_fp16.h>

#define NPTS  2048
#define BATCH 4
#define NBP   8192      // BATCH*NPTS
#define MROWS 24576     // NBP*3
#define KNN_K 16

typedef short bf16x8 __attribute__((ext_vector_type(8)));
typedef float f32x4  __attribute__((ext_vector_type(4)));

// split fp32 into bf16 hi + bf16 lo (RTNE), x ~= hi + lo to ~2^-17 rel
static __device__ __forceinline__ void split_bf16(float a, unsigned short& h, unsigned short& l)
{
    unsigned u = __float_as_uint(a);
    unsigned hr = (u + 0x7FFFu + ((u >> 16) & 1u)) & 0xFFFF0000u;
    h = (unsigned short)(hr >> 16);
    float rem = a - __uint_as_float(hr);
    unsigned v = __float_as_uint(rem);
    l = (unsigned short)((v + 0x7FFFu + ((v >> 16) & 1u)) >> 16);
}

static __device__ __forceinline__ float bf2(unsigned short h, unsigned short l)
{
    return __uint_as_float((unsigned)h << 16) + __uint_as_float((unsigned)l << 16);
}

// fast lna scale: s = 0.8*dot/(dsq+eps) via v_rcp_f32 (<=2ulp; tolerance slack huge)
static __device__ __forceinline__ float lna_scale(float dot, float dsq)
{
    return (dot < 0.f) ? 0.8f * dot * __builtin_amdgcn_rcpf(dsq + 1e-6f) : 0.f;
}

static __device__ __forceinline__ unsigned long long shfl_xor_u64(unsigned long long v, int mask)
{
    unsigned lo = (unsigned)v, hi = (unsigned)(v >> 32);
    lo = (unsigned)__shfl_xor((int)lo, mask, 64);
    hi = (unsigned)__shfl_xor((int)hi, mask, 64);
    return ((unsigned long long)hi << 32) | lo;
}

// XCD-confinement swizzle (bijection; wrong mapping assumption = speed-neutral)
static __device__ __forceinline__ int xcd_swizzle(int i, int G)
{
    int batch  = (i >> 1) & 3;
    int within = ((i >> 3) << 1) | (i & 1);
    return batch * (G >> 2) + within;
}

// interleaved edge-weight element: rows j<2O: AF0 AD0 AF1 AD1...; j>=2O: GF0 GD0...
static __device__ __forceinline__ float wbig_val(const float* __restrict__ Wf,
                                                 const float* __restrict__ Wd,
                                                 int j, int c, int O, int C)
{
    if (j < 2 * O) {
        int o = j >> 1;
        return (j & 1) ? Wd[o * 2 * C + c] : Wf[o * 2 * C + c];
    }
    int o = (j - 2 * O) >> 1;
    return (j & 1) ? (Wd[o * 2 * C + C + c] - Wd[o * 2 * C + c])
                   : (Wf[o * 2 * C + C + c] - Wf[o * 2 * C + c]);
}

// fragment-order permute for NT MFMA B operands read straight from global:
// value(r,c) stored at (((c>>5)*RB + (r>>4))*64 + ((c>>3)&3)*16 + (r&15))*8 + (c&7)
// so fragment (rowblock, kstep) loads are base + lane*8 -> coalesced 1KB/wave.
static __device__ __forceinline__ int frag_ix(int r, int c, int RB)
{
    return (((c >> 5) * RB + (r >> 4)) * 64 + ((c >> 3) & 3) * 16 + (r & 15)) * 8 + (c & 7);
}

// ---------------------------------------------------------------------------
// prep+knn mega-kernel: blocks [0, NBP/4) run KNN (4 waves, one query per
// wave); remaining blocks run layer-1 GEMM + all weight builds.
// Wc frag-ordered (RB=12). R17: Wi1 frag-ordered 256x128 (RB=16, k<128 only --
// the k>=128 part lives in ym); Wi2 stacked f/d halves frag-ordered (RB=32).
// ---------------------------------------------------------------------------
#define PC0 1572864          // l1: MROWS*64 -> AH/AG
#define PC1 (PC0 + 4096)     // Wb2 (O=32,C=16,Kp=32)
#define PC2 (PC1 + 8192)     // Wb3 (O=64,C=32,Kp=32)
#define PC3 (PC2 + 32768)    // Wb4 (O=128,C=64,Kp=64)
#define PC4 (PC3 + 49152)    // Wc frag-ordered (192 x 256)
#define PC5 (PC4 + 32768)    // Wi1 frag-ordered (256 x 128)
#define PC6 (PC5 + 65536)    // Wi2 stacked frag-ordered (512 x 128)
#define KNN_BLOCKS (NBP / 4)       // 2048
#define PREP_BLOCKS (PC6 / 256)    // 6896

__global__ __launch_bounds__(256) void prep_knn_kernel(
    const float* __restrict__ x, int* __restrict__ idx,
    __half* __restrict__ AH, float* __restrict__ AG,
    const float* __restrict__ w1f, const float* __restrict__ w1d,
    const float* __restrict__ w2f, const float* __restrict__ w2d,
    unsigned short* __restrict__ Wb2h, unsigned short* __restrict__ Wb2l,
    const float* __restrict__ w3f, const float* __restrict__ w3d,
    unsigned short* __restrict__ Wb3h, unsigned short* __restrict__ Wb3l,
    const float* __restrict__ w4f, const float* __restrict__ w4d,
    unsigned short* __restrict__ Wb4h, unsigned short* __restrict__ Wb4l,
    const float* __restrict__ wcf, const float* __restrict__ wcd,
    unsigned short* __restrict__ Wch, unsigned short* __restrict__ Wcl,
    const float* __restrict__ wi1f, const float* __restrict__ wi1d,
    unsigned short* __restrict__ Wi1h, unsigned short* __restrict__ Wi1l,
    const float* __restrict__ wi2f, const float* __restrict__ wi2d,
    unsigned short* __restrict__ Wi2h, unsigned short* __restrict__ Wi2l)
{
    __shared__ unsigned ksh[4][64 * 34];
    if (blockIdx.x < KNN_BLOCKS) {
        // ---- KNN: one query per wave, keys in this wave's LDS slice ----
        const int t  = threadIdx.x & 63;
        const int wq = threadIdx.x >> 6;
        const int bn = blockIdx.x * 4 + wq;
        const int b = bn >> 11;
        const int n = bn & (NPTS - 1);
        const float* xb = x + b * 3 * NPTS;
        const float qx = xb[n], qy = xb[NPTS + n], qz = xb[2 * NPTS + n];
        const float sqn = fmaf(qz, qz, fmaf(qy, qy, qx * qx));
        unsigned* ks = &ksh[wq][t * 34];

        unsigned gm[4];
        int ga[4];
#pragma unroll
        for (int g = 0; g < 4; g++) {
            unsigned kk[8];
#pragma unroll
            for (int j = 0; j < 8; j++) {
                const int i = g * 8 + j;
                const int m = (i << 6) + t;
                float mx = xb[m], my = xb[NPTS + m], mz = xb[2 * NPTS + m];
                float sqm = fmaf(mz, mz, fmaf(my, my, mx * mx));
                float dt  = fmaf(qz, mz, fmaf(qy, my, qx * mx));
                float d2  = sqn + sqm - 2.0f * dt;
                unsigned u = __float_as_uint(d2);
                u ^= (u & 0x80000000u) ? 0xFFFFFFFFu : 0x80000000u;  // monotone map
                kk[j] = u;
            }
            *(uint2*)&ks[g * 8 + 0] = make_uint2(kk[0], kk[1]);
            *(uint2*)&ks[g * 8 + 2] = make_uint2(kk[2], kk[3]);
            *(uint2*)&ks[g * 8 + 4] = make_uint2(kk[4], kk[5]);
            *(uint2*)&ks[g * 8 + 6] = make_uint2(kk[6], kk[7]);
            unsigned bg = kk[0];
            int ba = g * 8;
#pragma unroll
            for (int j = 1; j < 8; j++) {
                if (kk[j] < bg) { bg = kk[j]; ba = g * 8 + j; }
            }
            gm[g] = bg; ga[g] = ba;
        }
        unsigned lm = gm[0];
        int il = ga[0];
#pragma unroll
        for (int g = 1; g < 4; g++) if (gm[g] < lm) { lm = gm[g]; il = ga[g]; }

        unsigned long long pk = ((unsigned long long)lm << 32) | (unsigned)((il << 6) | t);
        int res = -1;
        for (int r = 0; r < KNN_K; r++) {
            unsigned long long w = pk;
#pragma unroll
            for (int off = 32; off > 0; off >>= 1) {
                unsigned long long o = shfl_xor_u64(w, off);
                w = (o < w) ? o : w;
            }
            if (t == r) res = (int)(w & 0xFFFFFFFFull);

            if (pk == w) {                    // exactly one owner lane (m unique)
                ks[il] = 0xFFFFFFFFu;
                const int g = il >> 3;
                unsigned bg = ks[g * 8];
                int ba = g * 8;
#pragma unroll
                for (int j = 1; j < 8; j++) {
                    unsigned kv = ks[g * 8 + j];
                    if (kv < bg) { bg = kv; ba = g * 8 + j; }
                }
                gm[g] = bg; ga[g] = ba;
                lm = gm[0]; il = ga[0];
#pragma unroll
                for (int g2 = 1; g2 < 4; g2++) if (gm[g2] < lm) { lm = gm[g2]; il = ga[g2]; }
                pk = ((unsigned long long)lm << 32) | (unsigned)((il << 6) | t);
            }
        }
        if (t < KNN_K) idx[bn * KNN_K + t] = res;
        return;
    }

    // ---- prep: layer-1 + weight builds ----
    const int i = (blockIdx.x - KNN_BLOCKS) * 256 + threadIdx.x;
    if (i < PC0) {
        int o = i & 63;
        int row = i >> 6;
        int v = row % 3;
        int gp = row / 3;
        int b = gp >> 11;
        int n = gp & (NPTS - 1);
        float xv = x[(b * 3 + v) * NPTS + n];
        float wv = wbig_val(w1f, w1d, o, 0, 16, 1);
        float val = xv * wv;
        if (o < 32) AH[(size_t)row * 32 + o] = __float2half(val);
        else        AG[(size_t)row * 32 + o - 32] = val;
    } else if (i < PC6) {
        float v = 0.f;
        unsigned short *ph, *pl;
        int ix;
        if (i < PC1) {            // Wb2: O=32,C=16,Kpad=32
            ix = i - PC0;
            int c = ix & 31, j = ix >> 5;
            if (c < 16) v = wbig_val(w2f, w2d, j, c, 32, 16);
            ph = Wb2h; pl = Wb2l;
        } else if (i < PC2) {     // Wb3: O=64,C=32,Kpad=32
            ix = i - PC1;
            int c = ix & 31, j = ix >> 5;
            v = wbig_val(w3f, w3d, j, c, 64, 32);
            ph = Wb3h; pl = Wb3l;
        } else if (i < PC3) {     // Wb4: O=128,C=64,Kpad=64
            ix = i - PC2;
            int c = ix & 63, j = ix >> 6;
            v = wbig_val(w4f, w4d, j, c, 128, 64);
            ph = Wb4h; pl = Wb4l;
        } else if (i < PC4) {     // Wc frag-ordered: 192 rows x 256 k (RB=12)
            ix = i - PC3;
            int c = ix & 255, r = ix >> 8;
            if (c < 240) {
                if (r < 128) v = wcf[r * 240 + c];
                else if (r < 129) v = wcd[(r - 128) * 240 + c];
            }
            ph = Wch; pl = Wcl;
            ix = frag_ix(r, c, 12);
        } else if (i < PC5) {     // Wi1 frag-ordered: 256 rows x 128 k (RB=16)
            ix = i - PC4;
            int c = ix & 127, r = ix >> 7;
            if (r < 128) v = wi1f[r * 256 + c];
            else v = wi1d[(r - 128) * 256 + c];
            ph = Wi1h; pl = Wi1l;
            ix = frag_ix(r, c, 16);
        } else {                  // Wi2 stacked f(0-255)/d(256-511), frag-ordered (RB=32)
            ix = i - PC5;
            int c = ix & 127, r = ix >> 7;
            if (r < 256) v = wi2f[r * 128 + c];
            else v = wi2d[(r - 256) * 128 + c];
            ph = Wi2h; pl = Wi2l;
            ix = frag_ix(r, c, 32);
        }
        unsigned short h, l;
        split_bf16(v, h, l);
        ph[ix] = h; pl[ix] = l;
    }
}

// ---------------------------------------------------------------------------
// Fused edge + gemm (layers 2 and 3). Block = 16 points (48 rows), 4 waves.
// ---------------------------------------------------------------------------
template <int OIN, int NF>
__global__ __launch_bounds__(256, 3) void edge_gemm_kernel(
    const __half* __restrict__ AHin, const float* __restrict__ AGin,
    const int* __restrict__ idx,
    unsigned short* __restrict__ X240h, unsigned short* __restrict__ X240l, int ooff,
    const unsigned short* __restrict__ Wh, const unsigned short* __restrict__ Wl,
    __half* __restrict__ OUTA, float* __restrict__ OUTG)
{
    constexpr int PTS = 16;
    constexpr int NC = NF * 64;        // gemm output cols (2*twoO_out)
    constexpr int twoO = NC / 2;
    constexpr int LDW = 40;            // W LDS row stride (u16)
    constexpr int CPT = OIN / 16;      // channels per thread: 1 (O=16) or 2 (O=32)
    constexpr int twoOin = 2 * OIN;

    __shared__ unsigned short Xsh[48][32];
    __shared__ unsigned short Xsl[48][32];
    __shared__ unsigned short wbh[NC][LDW];
    __shared__ unsigned short wbl[NC][LDW];
    __shared__ int sIdx[PTS][KNN_K];

    const int lb = xcd_swizzle(blockIdx.x, gridDim.x);
    const int tid = threadIdx.x;

    // stage W + idx (W has no dependence on edge outputs)
    for (int rr = tid; rr < NC; rr += 256) {
#pragma unroll
        for (int scc = 0; scc < 4; scc++) {
            *(uint4*)&wbh[rr][scc * 8] = *(const uint4*)(Wh + (size_t)rr * 32 + scc * 8);
            *(uint4*)&wbl[rr][scc * 8] = *(const uint4*)(Wl + (size_t)rr * 32 + scc * 8);
        }
    }
    for (int j = tid; j < PTS * KNN_K; j += 256)
        sIdx[j >> 4][j & 15] = idx[(lb * PTS + (j >> 4)) * KNN_K + (j & 15)];
    __syncthreads();

    // ---- edge phase: 16 threads per point, CPT channels per thread ----
    const int op = tid & 15;
    const int pt = tid >> 4;
    const int gp = lb * PTS + pt;
    const int b = gp >> 11;
    const int rown = gp * 3;
    const int bbase = (b << 11) * 3;

    float cg[3][2 * CPT];
#pragma unroll
    for (int v = 0; v < 3; v++) {
        if constexpr (CPT == 2) {
            float4 c4 = *(const float4*)&AGin[(size_t)(rown + v) * twoOin + 4 * op];
            cg[v][0] = c4.x; cg[v][1] = c4.y; cg[v][2] = c4.z; cg[v][3] = c4.w;
        } else {
            float2 c2 = *(const float2*)&AGin[(size_t)(rown + v) * twoOin + 2 * op];
            cg[v][0] = c2.x; cg[v][1] = c2.y;
        }
    }
    float am[CPT][3];
#pragma unroll
    for (int c0 = 0; c0 < CPT; c0++) { am[c0][0] = 0.f; am[c0][1] = 0.f; am[c0][2] = 0.f; }

#pragma unroll 2
    for (int k = 0; k < KNN_K; k++) {
        const int m = sIdx[pt][k];
        const __half* base = AHin + (size_t)(bbase + m * 3) * twoOin + 2 * CPT * op;
        float e[3][2 * CPT];
#pragma unroll
        for (int v = 0; v < 3; v++) {
            if constexpr (CPT == 2) {
                uint2 u = *(const uint2*)(base + (size_t)v * twoOin);
                float2 x0 = __half22float2(*(__half2*)&u.x);
                float2 x1 = __half22float2(*(__half2*)&u.y);
                e[v][0] = x0.x; e[v][1] = x0.y; e[v][2] = x1.x; e[v][3] = x1.y;
            } else {
                unsigned u = *(const unsigned*)(base + (size_t)v * twoOin);
                float2 x0 = __half22float2(*(__half2*)&u);
                e[v][0] = x0.x; e[v][1] = x0.y;
            }
        }
#pragma unroll
        for (int c0 = 0; c0 < CPT; c0++) {
            float p0 = e[0][2 * c0] + cg[0][2 * c0], d0 = e[0][2 * c0 + 1] + cg[0][2 * c0 + 1];
            float p1 = e[1][2 * c0] + cg[1][2 * c0], d1 = e[1][2 * c0 + 1] + cg[1][2 * c0 + 1];
            float p2 = e[2][2 * c0] + cg[2][2 * c0], d2 = e[2][2 * c0 + 1] + cg[2][2 * c0 + 1];
            float dot = fmaf(p2, d2, fmaf(p1, d1, p0 * d0));
            float dsq = fmaf(d2, d2, fmaf(d1, d1, d0 * d0));
            float s = lna_scale(dot, dsq);
            am[c0][0] += fmaf(-s, d0, p0);
            am[c0][1] += fmaf(-s, d1, p1);
            am[c0][2] += fmaf(-s, d2, p2);
        }
    }

    // mean, write-through to X240, stage split-bf16 A-tile in LDS
#pragma unroll
    for (int v = 0; v < 3; v++) {
#pragma unroll
        for (int c0 = 0; c0 < CPT; c0++) {
            const int ch = CPT * op + c0;
            unsigned short h, l;
            split_bf16(am[c0][v] * 0.0625f, h, l);
            Xsh[pt * 3 + v][ch] = h;
            Xsl[pt * 3 + v][ch] = l;
            const size_t ob = (size_t)(rown + v) * 256 + ooff + ch;
            X240h[ob] = h; X240l[ob] = l;
        }
        if constexpr (CPT == 1) {      // zero-pad k = 16..32
            Xsh[pt * 3 + v][16 + op] = 0;
            Xsl[pt * 3 + v][16 + op] = 0;
        }
    }
    __syncthreads();

    // ---- gemm phase: one K-step (Kpad=32), waves split N ----
    const int lane = tid & 63;
    const int wv = tid >> 6;
    const int mr = lane & 15;
    const int q  = lane >> 4;

    f32x4 acc[3][NF];
#pragma unroll
    for (int a = 0; a < 3; a++)
#pragma unroll
        for (int c = 0; c < NF; c++) acc[a][c] = (f32x4){0.f, 0.f, 0.f, 0.f};

    bf16x8 ah[3], al[3], bh[NF], bl[NF];
#pragma unroll
    for (int mf = 0; mf < 3; mf++) {
        ah[mf] = *(const bf16x8*)&Xsh[mf * 16 + mr][q * 8];
        al[mf] = *(const bf16x8*)&Xsl[mf * 16 + mr][q * 8];
    }
#pragma unroll
    for (int nf = 0; nf < NF; nf++) {
        const int wr = wv * 16 * NF + nf * 16 + mr;
        bh[nf] = *(const bf16x8*)&wbh[wr][q * 8];
        bl[nf] = *(const bf16x8*)&wbl[wr][q * 8];
    }
#pragma unroll
    for (int mf = 0; mf < 3; mf++)
#pragma unroll
        for (int nf = 0; nf < NF; nf++) {
            acc[mf][nf] = __builtin_amdgcn_mfma_f32_16x16x32_bf16(ah[mf], bh[nf], acc[mf][nf], 0, 0, 0);
            acc[mf][nf] = __builtin_amdgcn_mfma_f32_16x16x32_bf16(ah[mf], bl[nf], acc[mf][nf], 0, 0, 0);
            acc[mf][nf] = __builtin_amdgcn_mfma_f32_16x16x32_bf16(al[mf], bh[nf], acc[mf][nf], 0, 0, 0);
        }

    // epilogue: col split AH (fp16) / AG (fp32) is wave-uniform
    const int rbase = lb * 48;
#pragma unroll
    for (int nf = 0; nf < NF; nf++) {
        const int col = wv * 16 * NF + nf * 16 + mr;
#pragma unroll
        for (int mf = 0; mf < 3; mf++)
#pragma unroll
            for (int i = 0; i < 4; i++) {
                const int row = rbase + mf * 16 + q * 4 + i;
                const float val = acc[mf][nf][i];
                if (col < twoO) OUTA[(size_t)row * twoO + col] = __float2half(val);
                else            OUTG[(size_t)row * twoO + col - twoO] = val;
            }
    }
}

// ---------------------------------------------------------------------------
// Split-bf16 MFMA GEMM (NT), layer 4 only. Epilogue: col<twoO -> fp16 OUTA;
// else fp32 OUTG.
// ---------------------------------------------------------------------------
__global__ __launch_bounds__(256) void gemm_mfma(
    const unsigned short* __restrict__ Xh, const unsigned short* __restrict__ Xl,
    int ldx, int xoff,
    const unsigned short* __restrict__ Wh, const unsigned short* __restrict__ Wl,
    float* __restrict__ OUT, int ldo, int Nout, int Kpad,
    __half* __restrict__ OUTA, float* __restrict__ OUTG, int twoO)
{
    __shared__ unsigned short Ws[2][64][56];
    const int tid = threadIdx.x;
    const int bm = blockIdx.x * 256;
    const int bo = blockIdx.y * 64;
    const int lane = tid & 63;
    const int wv = tid >> 6;
    const int mr = lane & 15;
    const int q  = lane >> 4;

    f32x4 acc[4][4];
#pragma unroll
    for (int a = 0; a < 4; a++)
#pragma unroll
        for (int c = 0; c < 4; c++) acc[a][c] = (f32x4){0.f, 0.f, 0.f, 0.f};

    const int wr = tid >> 2;   // 0..63
    const int sc = tid & 3;    // k-chunk 0..3

    for (int k0 = 0; k0 < Kpad; k0 += 32) {
        {
            const uint4 vh = *(const uint4*)(Wh + (size_t)(bo + wr) * Kpad + k0 + sc * 8);
            const uint4 vl = *(const uint4*)(Wl + (size_t)(bo + wr) * Kpad + k0 + sc * 8);
            *(uint4*)&Ws[0][wr][sc * 8] = vh;
            *(uint4*)&Ws[1][wr][sc * 8] = vl;
        }
        __syncthreads();

        bf16x8 ah[4], al[4], bh[4], bl[4];
#pragma unroll
        for (int mf = 0; mf < 4; mf++) {
            const size_t xrow = (size_t)(bm + wv * 64 + mf * 16 + mr) * ldx + xoff + k0 + q * 8;
            ah[mf] = *(const bf16x8*)(Xh + xrow);
            al[mf] = *(const bf16x8*)(Xl + xrow);
        }
#pragma unroll
        for (int nf = 0; nf < 4; nf++) {
            bh[nf] = *(const bf16x8*)&Ws[0][nf * 16 + mr][q * 8];
            bl[nf] = *(const bf16x8*)&Ws[1][nf * 16 + mr][q * 8];
        }
#pragma unroll
        for (int mf = 0; mf < 4; mf++)
#pragma unroll
            for (int nf = 0; nf < 4; nf++) {
                acc[mf][nf] = __builtin_amdgcn_mfma_f32_16x16x32_bf16(ah[mf], bh[nf], acc[mf][nf], 0, 0, 0);
                acc[mf][nf] = __builtin_amdgcn_mfma_f32_16x16x32_bf16(ah[mf], bl[nf], acc[mf][nf], 0, 0, 0);
                acc[mf][nf] = __builtin_amdgcn_mfma_f32_16x16x32_bf16(al[mf], bh[nf], acc[mf][nf], 0, 0, 0);
            }
        __syncthreads();
    }

    // epilogue: D layout col=lane&15, row=q*4+i
    if (OUTA) {
#pragma unroll
        for (int nf = 0; nf < 4; nf++) {
            const int col = bo + nf * 16 + mr;
            if (col < twoO) {
#pragma unroll
                for (int mf = 0; mf < 4; mf++)
#pragma unroll
                    for (int i = 0; i < 4; i++) {
                        const int row = bm + wv * 64 + mf * 16 + q * 4 + i;
                        OUTA[(size_t)row * twoO + col] = __float2half(acc[mf][nf][i]);
                    }
            } else {
#pragma unroll
                for (int mf = 0; mf < 4; mf++)
#pragma unroll
                    for (int i = 0; i < 4; i++) {
                        const int row = bm + wv * 64 + mf * 16 + q * 4 + i;
                        OUTG[(size_t)row * twoO + col - twoO] = acc[mf][nf][i];
                    }
            }
        }
    } else {
#pragma unroll
        for (int nf = 0; nf < 4; nf++) {
            const int col = bo + nf * 16 + mr;
            if (col < Nout) {
#pragma unroll
                for (int mf = 0; mf < 4; mf++)
#pragma unroll
                    for (int i = 0; i < 4; i++) {
                        const int row = bm + wv * 64 + mf * 16 + q * 4 + i;
                        OUT[(size_t)row * ldo + col] = acc[mf][nf][i];
                    }
            }
        }
    }
}

// ---------------------------------------------------------------------------
// Edge conv + vec_lna + mean over K neighbors -> bf16 hi/lo output (ld 256).
// Only layer-3 edge (O=64) remains a standalone dispatch.
// ---------------------------------------------------------------------------
template <int O, int PT>
__global__ __launch_bounds__(256, 6) void edge_kernel(const __half* __restrict__ AH,
                                                      const float* __restrict__ AG,
                                                      const int* __restrict__ idx,
                                                      unsigned short* __restrict__ outh,
                                                      unsigned short* __restrict__ outl,
                                                      int ooff)
{
    constexpr int TP = O / 2;          // threads per point
    constexpr int twoO = 2 * O;
    const int lb = xcd_swizzle(blockIdx.x, gridDim.x);
    const int tid = threadIdx.x;
    const int op = tid % TP;
    const int pt = tid / TP;
    const int gp = lb * PT + pt;
    const int b = gp >> 11;
    __shared__ int sIdx[PT][KNN_K];
    for (int j = tid; j < PT * KNN_K; j += 256)
        sIdx[j >> 4][j & 15] = idx[(lb * PT + (j >> 4)) * KNN_K + (j & 15)];
    __syncthreads();
    const int rown = gp * 3;
    const float4 c0 = *(const float4*)&AG[(size_t)(rown + 0) * twoO + 4 * op];
    const float4 c1 = *(const float4*)&AG[(size_t)(rown + 1) * twoO + 4 * op];
    const float4 c2 = *(const float4*)&AG[(size_t)(rown + 2) * twoO + 4 * op];
    float ax0 = 0.f, ax1 = 0.f, ax2 = 0.f;   // o = 2op
    float ay0 = 0.f, ay1 = 0.f, ay2 = 0.f;   // o = 2op+1
    const int bbase = (b << 11) * 3;
#pragma unroll 2
    for (int k = 0; k < KNN_K; k++) {
        int m = sIdx[pt][k];
        const __half* base = AH + (size_t)(bbase + m * 3) * twoO + 4 * op;
        uint2 u0 = *(const uint2*)(base);
        uint2 u1 = *(const uint2*)(base + twoO);
        uint2 u2 = *(const uint2*)(base + 2 * twoO);
        float2 e0 = __half22float2(*(__half2*)&u0.x);
        float2 f0 = __half22float2(*(__half2*)&u0.y);
        float2 e1 = __half22float2(*(__half2*)&u1.x);
        float2 f1 = __half22float2(*(__half2*)&u1.y);
        float2 e2 = __half22float2(*(__half2*)&u2.x);
        float2 f2 = __half22float2(*(__half2*)&u2.y);
        {
            float p0 = e0.x + c0.x, d0 = e0.y + c0.y;
            float p1 = e1.x + c1.x, d1 = e1.y + c1.y;
            float p2 = e2.x + c2.x, d2 = e2.y + c2.y;
            float dot = fmaf(p2, d2, fmaf(p1, d1, p0 * d0));
            float dsq = fmaf(d2, d2, fmaf(d1, d1, d0 * d0));
            float s = lna_scale(dot, dsq);
            ax0 += fmaf(-s, d0, p0);
            ax1 += fmaf(-s, d1, p1);
            ax2 += fmaf(-s, d2, p2);
        }
        {
            float p0 = f0.x + c0.z, d0 = f0.y + c0.w;
            float p1 = f1.x + c1.z, d1 = f1.y + c1.w;
            float p2 = f2.x + c2.z, d2 = f2.y + c2.w;
            float dot = fmaf(p2, d2, fmaf(p1, d1, p0 * d0));
            float dsq = fmaf(d2, d2, fmaf(d1, d1, d0 * d0));
            float s = lna_scale(dot, dsq);
            ay0 += fmaf(-s, d0, p0);
            ay1 += fmaf(-s, d1, p1);
            ay2 += fmaf(-s, d2, p2);
        }
    }
    float rx[3] = { ax0 * 0.0625f, ax1 * 0.0625f, ax2 * 0.0625f };
    float ry[3] = { ay0 * 0.0625f, ay1 * 0.0625f, ay2 * 0.0625f };
#pragma unroll
    for (int v = 0; v < 3; v++) {
        unsigned short hx, lx, hy, ly;
        split_bf16(rx[v], hx, lx);
        split_bf16(ry[v], hy, ly);
        const size_t ob = (size_t)(rown + v) * 256 + ooff + 2 * op;
        *(unsigned*)(outh + ob) = (unsigned)hx | ((unsigned)hy << 16);
        *(unsigned*)(outl + ob) = (unsigned)lx | ((unsigned)ly << 16);
    }
}

// ---------------------------------------------------------------------------
// Fused layer-4 edge (O=128) + wc GEMM + lna. Block = 16 points.
// Wc B-frags read via frag-order (coalesced); tb unions the x4 LDS region.
// ---------------------------------------------------------------------------
#define EW_LDX 136   // x4 u16 stride
#define EW_LDT 133   // tb fp32 stride
__global__ __launch_bounds__(256, 4) void edge_wc_kernel(
    const __half* __restrict__ AHin, const float* __restrict__ AGin,   // ld 256
    const int* __restrict__ idx,
    const unsigned short* __restrict__ Xh, const unsigned short* __restrict__ Xl, // X240 ld 256 (cols 0..111)
    const unsigned short* __restrict__ Wh, const unsigned short* __restrict__ Wl, // Wc frag-ordered 192x256
    unsigned short* __restrict__ oh, unsigned short* __restrict__ ol,  // xc2 ld 128
    float* __restrict__ part2)
{
    // union: x4h(13056) + x4l(13056) = 26112B; tb needs 48*133*4 = 25536B
    __shared__ __align__(16) char smem[48 * EW_LDX * 2 * 2];
    unsigned short (*x4h)[EW_LDX] = (unsigned short (*)[EW_LDX])smem;
    unsigned short (*x4l)[EW_LDX] = (unsigned short (*)[EW_LDX])(smem + 48 * EW_LDX * 2);
    float* tb = (float*)smem;
    __shared__ int sIdx[16][KNN_K];

    const int lb = xcd_swizzle(blockIdx.x, gridDim.x);
    const int tid = threadIdx.x;

    for (int j = tid; j < 16 * KNN_K; j += 256)
        sIdx[j >> 4][j & 15] = idx[(lb * 16 + (j >> 4)) * KNN_K + (j & 15)];
    __syncthreads();

    // ---- edge phase: 16 thr/pt, 8 channels/thr ----
    {
        const int op = tid & 15;
        const int pt = tid >> 4;
        const int gp = lb * 16 + pt;
        const int b = gp >> 11;
        const int rown = gp * 3;
        const int bbase = (b << 11) * 3;

        float cg[3][16];
#pragma unroll
        for (int v = 0; v < 3; v++) {
            const float* ag = &AGin[(size_t)(rown + v) * 256 + 16 * op];
#pragma unroll
            for (int t = 0; t < 4; t++) {
                float4 c4 = *(const float4*)(ag + 4 * t);
                cg[v][4 * t + 0] = c4.x; cg[v][4 * t + 1] = c4.y;
                cg[v][4 * t + 2] = c4.z; cg[v][4 * t + 3] = c4.w;
            }
        }
        float am[8][3];
#pragma unroll
        for (int c0 = 0; c0 < 8; c0++) { am[c0][0] = 0.f; am[c0][1] = 0.f; am[c0][2] = 0.f; }

        for (int k = 0; k < KNN_K; k++) {
            const int m = sIdx[pt][k];
            const __half* base = AHin + (size_t)(bbase + m * 3) * 256 + 16 * op;
            unsigned uw[3][8];
#pragma unroll
            for (int v = 0; v < 3; v++) {
                uint4 a  = *(const uint4*)(base + (size_t)v * 256);
                uint4 bq = *(const uint4*)(base + (size_t)v * 256 + 8);
                uw[v][0] = a.x;  uw[v][1] = a.y;  uw[v][2] = a.z;  uw[v][3] = a.w;
                uw[v][4] = bq.x; uw[v][5] = bq.y; uw[v][6] = bq.z; uw[v][7] = bq.w;
            }
#pragma unroll
            for (int c0 = 0; c0 < 8; c0++) {
                float2 e0 = __half22float2(*(__half2*)&uw[0][c0]);
                float2 e1 = __half22float2(*(__half2*)&uw[1][c0]);
                float2 e2 = __half22float2(*(__half2*)&uw[2][c0]);
                float p0 = e0.x + cg[0][2 * c0], d0 = e0.y + cg[0][2 * c0 + 1];
                float p1 = e1.x + cg[1][2 * c0], d1 = e1.y + cg[1][2 * c0 + 1];
                float p2 = e2.x + cg[2][2 * c0], d2 = e2.y + cg[2][2 * c0 + 1];
                float dot = fmaf(p2, d2, fmaf(p1, d1, p0 * d0));
                float dsq = fmaf(d2, d2, fmaf(d1, d1, d0 * d0));
                float s = lna_scale(dot, dsq);
                am[c0][0] += fmaf(-s, d0, p0);
                am[c0][1] += fmaf(-s, d1, p1);
                am[c0][2] += fmaf(-s, d2, p2);
            }
        }
#pragma unroll
        for (int v = 0; v < 3; v++)
#pragma unroll
            for (int c0 = 0; c0 < 8; c0++) {
                unsigned short h, l;
                split_bf16(am[c0][v] * 0.0625f, h, l);
                x4h[pt * 3 + v][8 * op + c0] = h;
                x4l[pt * 3 + v][8 * op + c0] = l;
            }
    }
    __syncthreads();

    // ---- wc GEMM: K=256 pad, A source select, B frag-ordered from global ----
    const int lane = tid & 63;
    const int wv = tid >> 6;
    const int mr = lane & 15;
    const int q  = lane >> 4;
    const int rbase = lb * 48;

    f32x4 acc[3][3];
#pragma unroll
    for (int a = 0; a < 3; a++)
#pragma unroll
        for (int c = 0; c < 3; c++) acc[a][c] = (f32x4){0.f, 0.f, 0.f, 0.f};

    for (int k0 = 0; k0 < 256; k0 += 32) {
        const int kb = k0 + q * 8;
        bf16x8 ah[3], al[3], bh[3], bl[3];
#pragma unroll
        for (int mf = 0; mf < 3; mf++) {
            const int row = mf * 16 + mr;
            if (kb >= 112) {
                if (kb >= 240) {
                    ah[mf] = (bf16x8){0, 0, 0, 0, 0, 0, 0, 0};
                    al[mf] = (bf16x8){0, 0, 0, 0, 0, 0, 0, 0};
                } else {
                    ah[mf] = *(const bf16x8*)&x4h[row][kb - 112];
                    al[mf] = *(const bf16x8*)&x4l[row][kb - 112];
                }
            } else {
                const size_t xr = (size_t)(rbase + row) * 256 + kb;
                ah[mf] = *(const bf16x8*)(Xh + xr);
                al[mf] = *(const bf16x8*)(Xl + xr);
            }
        }
#pragma unroll
        for (int nf = 0; nf < 3; nf++) {
            const size_t wri = (size_t)((((k0 >> 5) * 12) + wv * 3 + nf) * 64 + lane) * 8;
            bh[nf] = *(const bf16x8*)(Wh + wri);
            bl[nf] = *(const bf16x8*)(Wl + wri);
        }
#pragma unroll
        for (int mf = 0; mf < 3; mf++)
#pragma unroll
            for (int nf = 0; nf < 3; nf++) {
                acc[mf][nf] = __builtin_amdgcn_mfma_f32_16x16x32_bf16(ah[mf], bh[nf], acc[mf][nf], 0, 0, 0);
                acc[mf][nf] = __builtin_amdgcn_mfma_f32_16x16x32_bf16(ah[mf], bl[nf], acc[mf][nf], 0, 0, 0);
                acc[mf][nf] = __builtin_amdgcn_mfma_f32_16x16x32_bf16(al[mf], bh[nf], acc[mf][nf], 0, 0, 0);
            }
    }
    __syncthreads();   // x4 dead; tb overlays it

    // stage cols 0..128 (p cols + shared d col)
#pragma unroll
    for (int mf = 0; mf < 3; mf++)
#pragma unroll
        for (int nf = 0; nf < 3; nf++) {
            const int col = wv * 48 + nf * 16 + mr;
            if (col <= 128) {
#pragma unroll
                for (int i = 0; i < 4; i++)
                    tb[(mf * 16 + q * 4 + i) * EW_LDT + col] = acc[mf][nf][i];
            }
        }
    __syncthreads();

    const int bp0 = lb * 16;
    float vacc[3] = {0.f, 0.f, 0.f};
#pragma unroll
    for (int it = 0; it < 8; it++) {
        const int item = it * 256 + tid;   // 2048 = 16 pts x 128 o
        const int o = item & 127;
        const int pt = item >> 7;
        float p[3], d[3];
#pragma unroll
        for (int v = 0; v < 3; v++) {
            const int r = pt * 3 + v;
            p[v] = tb[r * EW_LDT + o];
            d[v] = tb[r * EW_LDT + 128];
        }
        float dot = fmaf(p[2], d[2], fmaf(p[1], d[1], p[0] * d[0]));
        float dsq = fmaf(d[2], d[2], fmaf(d[1], d[1], d[0] * d[0]));
        float s = lna_scale(dot, dsq);
#pragma unroll
        for (int v = 0; v < 3; v++) {
            float val = fmaf(-s, d[v], p[v]);
            vacc[v] += val;
            unsigned short h, l;
            split_bf16(val, h, l);
            const size_t ob = ((size_t)(bp0 + pt) * 3 + v) * 128 + o;
            oh[ob] = h; ol[ob] = l;
        }
    }

    __syncthreads();
    tb[tid] = vacc[0]; tb[256 + tid] = vacc[1]; tb[512 + tid] = vacc[2];
    __syncthreads();
    if (tid < 128) {
#pragma unroll
        for (int v = 0; v < 3; v++)
            part2[(size_t)lb * 384 + v * 128 + tid] =
                tb[v * 256 + tid] + tb[v * 256 + tid + 128];
    }
}

// ---------------------------------------------------------------------------
// xm reduce + ym: part2[512][3][128] -> xm (bf16-pair, 12x128) AND
// ym[12][256] = xm @ Wi1stack[:,128:256]^T (constant K>=128 part of wi1).
// ---------------------------------------------------------------------------
__global__ __launch_bounds__(128) void xm_reduce_ym_kernel(
    const float* __restrict__ part2,
    unsigned short* __restrict__ xmh, unsigned short* __restrict__ xml,
    const float* __restrict__ wi1f, const float* __restrict__ wi1d,
    float* __restrict__ ym)
{
    __shared__ float xs[128];
    const int bv = blockIdx.x;       // 12 = b*3+v
    const int b = bv / 3;
    const int v = bv % 3;
    const int o = threadIdx.x;       // 128
    float acc = 0.f;
    for (int i = 0; i < 128; i++)
        acc += part2[(size_t)(b * 128 + i) * 384 + v * 128 + o];
    const float m = acc * (1.f / 2048.f);
    unsigned short h, l;
    split_bf16(m, h, l);
    xmh[bv * 128 + o] = h;
    xml[bv * 128 + o] = l;
    xs[o] = m;
    __syncthreads();
#pragma unroll
    for (int half = 0; half < 2; half++) {
        const int oo = half * 128 + o;
        const float* wrow = (oo < 128) ? (wi1f + (size_t)oo * 256 + 128)
                                       : (wi1d + (size_t)(oo - 128) * 256 + 128);
        float s = 0.f;
        for (int c = 0; c < 128; c++) s = fmaf(wrow[c], xs[c], s);
        ym[(size_t)bv * 256 + oo] = s;
    }
}

// ---------------------------------------------------------------------------
// R17 fused wi1 + wi2 + inv with PADDED-M layout: 16 points x 4 rows (v=0..2
// + zero pad), so each lane's accumulator holds a complete point-triple
// (point = mf*4+q, v = i). Waves pair (p,d) N-fragments: p at col o, d at
// col 128+o in the SAME lane. Both lna epilogues + inv run entirely in
// registers -- no PD tile, no wt tile, 1 barrier total.
// Phase 1: B frag-ordered from global (Wi1 256x128, RB=16); A = xc2.
// Phase 2: two N-half passes (acc pressure), Wi2 stacked frag-ordered RB=32.
// LDS: y1 only (64x136 u16 x2 = 34.8KB).
// ---------------------------------------------------------------------------
#define QI_LDY 136    // y1 u16 stride (64 padded rows)
__global__ __launch_bounds__(256, 3) void gemm_ii_kernel(
    const unsigned short* __restrict__ xch, const unsigned short* __restrict__ xcl, // ld 128
    const unsigned short* __restrict__ W1h, const unsigned short* __restrict__ W1l, // Wi1 frag 256x128
    const unsigned short* __restrict__ W2h, const unsigned short* __restrict__ W2l, // Wi2 frag 512x128
    const unsigned short* __restrict__ xmh, const unsigned short* __restrict__ xml,
    const float* __restrict__ ym,
    float* __restrict__ out)
{
    __shared__ __align__(16) unsigned short y1h[64][QI_LDY];
    __shared__ __align__(16) unsigned short y1l[64][QI_LDY];

    const int tid = threadIdx.x;
    const int lane = tid & 63;
    const int wv = tid >> 6;
    const int mr = lane & 15;
    const int q  = lane >> 4;
    const int lb = blockIdx.x;
    const int bp0 = lb * 16;          // first point of this block
    const int bb = bp0 >> 11;         // batch (uniform: 16 | 2048)

    // ---- phase 1: wi1 GEMM, M=64 padded, N=256 (wave pairs p/d), K=128 ----
    f32x4 acc[4][4];   // [mf][nf]: nf 0,1 = p cols wv*32+nf*16+mr; nf 2,3 = d
#pragma unroll
    for (int a = 0; a < 4; a++)
#pragma unroll
        for (int c = 0; c < 4; c++) acc[a][c] = (f32x4){0.f, 0.f, 0.f, 0.f};

    for (int k0 = 0; k0 < 128; k0 += 32) {
        bf16x8 ah[4], al[4];
#pragma unroll
        for (int mf = 0; mf < 4; mf++) {
            const int mrow = mf * 16 + mr;
            const int pt = mrow >> 2, v = mrow & 3;
            if (v < 3) {
                const size_t xr = (size_t)((bp0 + pt) * 3 + v) * 128 + k0 + q * 8;
                ah[mf] = *(const bf16x8*)(xch + xr);
                al[mf] = *(const bf16x8*)(xcl + xr);
            } else {
                ah[mf] = (bf16x8){0, 0, 0, 0, 0, 0, 0, 0};
                al[mf] = (bf16x8){0, 0, 0, 0, 0, 0, 0, 0};
            }
        }
        const int ks = k0 >> 5;
#pragma unroll
        for (int nf = 0; nf < 4; nf++) {
            const int rbI = (nf < 2) ? (wv * 2 + nf) : (8 + wv * 2 + (nf - 2));
            const size_t wi = (size_t)((ks * 16 + rbI) * 64 + lane) * 8;
            const bf16x8 bh = *(const bf16x8*)(W1h + wi);
            const bf16x8 bl = *(const bf16x8*)(W1l + wi);
#pragma unroll
            for (int mf = 0; mf < 4; mf++) {
                acc[mf][nf] = __builtin_amdgcn_mfma_f32_16x16x32_bf16(ah[mf], bh, acc[mf][nf], 0, 0, 0);
                acc[mf][nf] = __builtin_amdgcn_mfma_f32_16x16x32_bf16(ah[mf], bl, acc[mf][nf], 0, 0, 0);
                acc[mf][nf] = __builtin_amdgcn_mfma_f32_16x16x32_bf16(al[mf], bh, acc[mf][nf], 0, 0, 0);
            }
        }
    }

    // epilogue 1 (in-register): lna(+ym) -> y1 LDS (padded rows; pad row = 0)
#pragma unroll
    for (int mf = 0; mf < 4; mf++) {
        const int pt = mf * 4 + q;
#pragma unroll
        for (int nfp = 0; nfp < 2; nfp++) {
            const int o = wv * 32 + nfp * 16 + mr;
            float p[3], d[3];
#pragma unroll
            for (int v = 0; v < 3; v++) {
                p[v] = acc[mf][nfp][v]     + ym[(size_t)(bb * 3 + v) * 256 + o];
                d[v] = acc[mf][nfp + 2][v] + ym[(size_t)(bb * 3 + v) * 256 + 128 + o];
            }
            float dot = fmaf(p[2], d[2], fmaf(p[1], d[1], p[0] * d[0]));
            float dsq = fmaf(d[2], d[2], fmaf(d[1], d[1], d[0] * d[0]));
            float s = lna_scale(dot, dsq);
#pragma unroll
            for (int v = 0; v < 3; v++) {
                unsigned short h, l;
                split_bf16(fmaf(-s, d[v], p[v]), h, l);
                y1h[pt * 4 + v][o] = h;
                y1l[pt * 4 + v][o] = l;
            }
            y1h[pt * 4 + 3][o] = 0;
            y1l[pt * 4 + 3][o] = 0;
        }
    }
    __syncthreads();

    // ---- phase 2: wi2 GEMM (M=64 padded, N=512) in two N-half passes ----
    for (int half = 0; half < 2; half++) {
        f32x4 accp[4][2], accd[4][2];
#pragma unroll
        for (int a = 0; a < 4; a++)
#pragma unroll
            for (int c = 0; c < 2; c++) {
                accp[a][c] = (f32x4){0.f, 0.f, 0.f, 0.f};
                accd[a][c] = (f32x4){0.f, 0.f, 0.f, 0.f};
            }

        for (int k0 = 0; k0 < 128; k0 += 32) {
            bf16x8 ah[4], al[4];
#pragma unroll
            for (int mf = 0; mf < 4; mf++) {
                ah[mf] = *(const bf16x8*)&y1h[mf * 16 + mr][k0 + q * 8];
                al[mf] = *(const bf16x8*)&y1l[mf * 16 + mr][k0 + q * 8];
            }
            const int ks = k0 >> 5;
#pragma unroll
            for (int nf2 = 0; nf2 < 2; nf2++) {
                const int rb = wv * 4 + half * 2 + nf2;
                const size_t wip = (size_t)((ks * 32 + rb) * 64 + lane) * 8;
                const size_t wid = (size_t)((ks * 32 + 16 + rb) * 64 + lane) * 8;
                const bf16x8 bph = *(const bf16x8*)(W2h + wip);
                const bf16x8 bpl = *(const bf16x8*)(W2l + wip);
                const bf16x8 bdh = *(const bf16x8*)(W2h + wid);
                const bf16x8 bdl = *(const bf16x8*)(W2l + wid);
#pragma unroll
                for (int mf = 0; mf < 4; mf++) {
                    accp[mf][nf2] = __builtin_amdgcn_mfma_f32_16x16x32_bf16(ah[mf], bph, accp[mf][nf2], 0, 0, 0);
                    accp[mf][nf2] = __builtin_amdgcn_mfma_f32_16x16x32_bf16(ah[mf], bpl, accp[mf][nf2], 0, 0, 0);
                    accp[mf][nf2] = __builtin_amdgcn_mfma_f32_16x16x32_bf16(al[mf], bph, accp[mf][nf2], 0, 0, 0);
                    accd[mf][nf2] = __builtin_amdgcn_mfma_f32_16x16x32_bf16(ah[mf], bdh, accd[mf][nf2], 0, 0, 0);
                    accd[mf][nf2] = __builtin_amdgcn_mfma_f32_16x16x32_bf16(ah[mf], bdl, accd[mf][nf2], 0, 0, 0);
                    accd[mf][nf2] = __builtin_amdgcn_mfma_f32_16x16x32_bf16(al[mf], bdh, accd[mf][nf2], 0, 0, 0);
                }
            }
        }

        // epilogue 2 (in-register): lna + inv -> out
#pragma unroll
        for (int mf = 0; mf < 4; mf++) {
            const int pt = mf * 4 + q;
            const int gp = bp0 + pt;
            const int n = gp & (NPTS - 1);
#pragma unroll
            for (int nf2 = 0; nf2 < 2; nf2++) {
                const int o = wv * 64 + half * 32 + nf2 * 16 + mr;
                float p[3], d[3], xc[3];
#pragma unroll
                for (int v = 0; v < 3; v++) {
                    p[v] = accp[mf][nf2][v];
                    d[v] = accd[mf][nf2][v];
                    if (o < 128) {
                        const size_t ix = (size_t)(gp * 3 + v) * 128 + o;
                        xc[v] = bf2(xch[ix], xcl[ix]);
                    } else {
                        const size_t ix = (size_t)(bb * 3 + v) * 128 + o - 128;
                        xc[v] = bf2(xmh[ix], xml[ix]);
                    }
                }
                float dot = fmaf(p[2], d[2], fmaf(p[1], d[1], p[0] * d[0]));
                float dsq = fmaf(d[2], d[2], fmaf(d[1], d[1], d[0] * d[0]));
                float s = lna_scale(dot, dsq);
                float inv = 0.f;
#pragma unroll
                for (int v = 0; v < 3; v++)
                    inv = fmaf(xc[v], fmaf(-s, d[v], p[v]), inv);
                out[((size_t)bb * 256 + o) * NPTS + n] = inv;
            }
        }
    }
}

// ---------------------------------------------------------------------------
// launch
// ---------------------------------------------------------------------------
extern "C" void kernel_launch(void* const* d_in, const int* in_sizes, int n_in,
                              void* d_out, int out_size, void* d_ws, size_t ws_size,
                              hipStream_t stream)
{
    const float* x    = (const float*)d_in[0];
    const float* w1f  = (const float*)d_in[1];
    const float* w1d  = (const float*)d_in[2];
    const float* w2f  = (const float*)d_in[3];
    const float* w2d  = (const float*)d_in[4];
    const float* w3f  = (const float*)d_in[5];
    const float* w3d  = (const float*)d_in[6];
    const float* w4f  = (const float*)d_in[7];
    const float* w4d  = (const float*)d_in[8];
    const float* wcf  = (const float*)d_in[9];
    const float* wcd  = (const float*)d_in[10];
    const float* wi1f = (const float*)d_in[11];
    const float* wi1d = (const float*)d_in[12];
    const float* wi2f = (const float*)d_in[13];
    const float* wi2d = (const float*)d_in[14];
    float* out = (float*)d_out;

    float* F = (float*)d_ws;
    size_t off = 0;
    float* AG = F + off;                          off += (size_t)MROWS * 512;  // AG1 = AG, AG2 = AG + MROWS*256
    __half* AH = (__half*)(F + off);              off += (size_t)MROWS * 128;  // AH1
    __half* AH2 = (__half*)(F + off);             off += (size_t)MROWS * 128;  // AH2 (ping-pong)
    unsigned short* X240h = (unsigned short*)(F + off); off += (size_t)MROWS * 128;
    unsigned short* X240l = (unsigned short*)(F + off); off += (size_t)MROWS * 128;
    unsigned short* xc2h  = (unsigned short*)(F + off); off += (size_t)MROWS * 64;  // ld 128
    unsigned short* xc2l  = (unsigned short*)(F + off); off += (size_t)MROWS * 64;
    unsigned short* Wb2h = (unsigned short*)(F + off); off += 2048;
    unsigned short* Wb2l = (unsigned short*)(F + off); off += 2048;
    unsigned short* Wb3h = (unsigned short*)(F + off); off += 4096;
    unsigned short* Wb3l = (unsigned short*)(F + off); off += 4096;
    unsigned short* Wb4h = (unsigned short*)(F + off); off += 16384;
    unsigned short* Wb4l = (unsigned short*)(F + off); off += 16384;
    unsigned short* Wch  = (unsigned short*)(F + off); off += 24576;
    unsigned short* Wcl  = (unsigned short*)(F + off); off += 24576;
    unsigned short* Wi1h = (unsigned short*)(F + off); off += 32768;
    unsigned short* Wi1l = (unsigned short*)(F + off); off += 32768;
    unsigned short* Wi2h = (unsigned short*)(F + off); off += 32768;
    unsigned short* Wi2l = (unsigned short*)(F + off); off += 32768;
    float* part2 = F + off;                       off += (size_t)512 * 384;    // wc per-block sums
    float* ym    = F + off;                       off += 12 * 256;             // wi1 xm-part GEMM
    unsigned short* xmph = (unsigned short*)(F + off); off += 768;   // 12*128 u16
    unsigned short* xmpl = (unsigned short*)(F + off); off += 768;
    int* idx    = (int*)(F + off);                off += NBP * KNN_K;
    float* AG2 = AG + (size_t)MROWS * 256;

    // merged prep (layer-1 + weight builds) + knn
    prep_knn_kernel<<<KNN_BLOCKS + PREP_BLOCKS, 256, 0, stream>>>(
        x, idx, AH, AG, w1f, w1d,
        w2f, w2d, Wb2h, Wb2l, w3f, w3d, Wb3h, Wb3l, w4f, w4d, Wb4h, Wb4l,
        wcf, wcd, Wch, Wcl, wi1f, wi1d, Wi1h, Wi1l, wi2f, wi2d, Wi2h, Wi2l);

    const int GM = MROWS / 256;   // 96

    // layer 1 edge + layer 2 gemm (fused): AH/AG (ld32) -> AH2/AG2 (ld64)
    edge_gemm_kernel<16, 2><<<NBP / 16, 256, 0, stream>>>(
        AH, AG, idx, X240h, X240l, 0, Wb2h, Wb2l, AH2, AG2);
    // layer 2 edge + layer 3 gemm (fused): AH2/AG2 (ld64) -> AH/AG (ld128)
    edge_gemm_kernel<32, 4><<<NBP / 16, 256, 0, stream>>>(
        AH2, AG2, idx, X240h, X240l, 16, Wb3h, Wb3l, AH, AG);
    // layer 3 edge
    edge_kernel<64, 8><<<NBP / 8, 256, 0, stream>>>(AH, AG, idx, X240h, X240l, 48);
    // layer 4: K=64, O=128 -> AH2/AG2 (ld 256)
    gemm_mfma<<<dim3(GM, 8), 256, 0, stream>>>(X240h, X240l, 256, 48, Wb4h, Wb4l, nullptr, 0, 512, 64, AH2, AG2, 256);

    // fused layer-4 edge + wc GEMM + lna -> xc2 + part2 (x4 never hits global)
    edge_wc_kernel<<<NBP / 16, 256, 0, stream>>>(AH2, AG2, idx, X240h, X240l,
                                                 Wch, Wcl, xc2h, xc2l, part2);

    // xm mean + ym precompute (single small dispatch)
    xm_reduce_ym_kernel<<<BATCH * 3, 128, 0, stream>>>(part2, xmph, xmpl, wi1f, wi1d, ym);

    // fused wi1 + wi2 + inv (y1 never hits global; all lna/inv in registers)
    gemm_ii_kernel<<<MROWS / 48, 256, 0, stream>>>(xc2h, xc2l, Wi1h, Wi1l,
                                                   Wi2h, Wi2l, xmph, xmpl, ym, out);

    (void)in_sizes; (void)n_in; (void)out_size; (void)ws_size;
}

// Round 7
// 251.982 us; speedup vs baseline: 1.1245x; 1.1245x over previous
//
#include <hip/hip_runtime.h>
#include <hip/hip_fp16.h>

#define NPTS  2048
#define BATCH 4
#define NBP   8192      // BATCH*NPTS
#define MROWS 24576     // NBP*3
#define KNN_K 16

typedef short bf16x8 __attribute__((ext_vector_type(8)));
typedef float f32x4  __attribute__((ext_vector_type(4)));

// split fp32 into bf16 hi + bf16 lo (RTNE), x ~= hi + lo to ~2^-17 rel
static __device__ __forceinline__ void split_bf16(float a, unsigned short& h, unsigned short& l)
{
    unsigned u = __float_as_uint(a);
    unsigned hr = (u + 0x7FFFu + ((u >> 16) & 1u)) & 0xFFFF0000u;
    h = (unsigned short)(hr >> 16);
    float rem = a - __uint_as_float(hr);
    unsigned v = __float_as_uint(rem);
    l = (unsigned short)((v + 0x7FFFu + ((v >> 16) & 1u)) >> 16);
}

static __device__ __forceinline__ float bf2(unsigned short h, unsigned short l)
{
    return __uint_as_float((unsigned)h << 16) + __uint_as_float((unsigned)l << 16);
}

// fast lna scale: s = 0.8*dot/(dsq+eps) via v_rcp_f32 (<=2ulp; tolerance slack huge)
static __device__ __forceinline__ float lna_scale(float dot, float dsq)
{
    return (dot < 0.f) ? 0.8f * dot * __builtin_amdgcn_rcpf(dsq + 1e-6f) : 0.f;
}

static __device__ __forceinline__ unsigned long long shfl_xor_u64(unsigned long long v, int mask)
{
    unsigned lo = (unsigned)v, hi = (unsigned)(v >> 32);
    lo = (unsigned)__shfl_xor((int)lo, mask, 64);
    hi = (unsigned)__shfl_xor((int)hi, mask, 64);
    return ((unsigned long long)hi << 32) | lo;
}

// XCD-confinement swizzle (bijection; wrong mapping assumption = speed-neutral)
static __device__ __forceinline__ int xcd_swizzle(int i, int G)
{
    int batch  = (i >> 1) & 3;
    int within = ((i >> 3) << 1) | (i & 1);
    return batch * (G >> 2) + within;
}

// interleaved edge-weight element: rows j<2O: AF0 AD0 AF1 AD1...; j>=2O: GF0 GD0...
static __device__ __forceinline__ float wbig_val(const float* __restrict__ Wf,
                                                 const float* __restrict__ Wd,
                                                 int j, int c, int O, int C)
{
    if (j < 2 * O) {
        int o = j >> 1;
        return (j & 1) ? Wd[o * 2 * C + c] : Wf[o * 2 * C + c];
    }
    int o = (j - 2 * O) >> 1;
    return (j & 1) ? (Wd[o * 2 * C + C + c] - Wd[o * 2 * C + c])
                   : (Wf[o * 2 * C + C + c] - Wf[o * 2 * C + c]);
}

// fragment-order permute for NT MFMA B operands read straight from global:
// value(r,c) stored at (((c>>5)*RB + (r>>4))*64 + ((c>>3)&3)*16 + (r&15))*8 + (c&7)
// so fragment (rowblock, kstep) loads are base + lane*8 -> coalesced 1KB/wave.
static __device__ __forceinline__ int frag_ix(int r, int c, int RB)
{
    return (((c >> 5) * RB + (r >> 4)) * 64 + ((c >> 3) & 3) * 16 + (r & 15)) * 8 + (c & 7);
}

// ---------------------------------------------------------------------------
// prep+knn mega-kernel: blocks [0, NBP/4) run KNN (4 waves, one query per
// wave); remaining blocks run layer-1 GEMM + all weight builds.
// Wc frag-ordered (RB=12). R18: Wi1 frag-ordered 256x128 (RB=16; k>=128 lives
// in ym) so gemm_ii phase 1 loads B direct from global (no LDS staging, no
// K-loop barriers). Wi2 interleaved rows frag-ordered (RB=32) as in R16.
// ---------------------------------------------------------------------------
#define PC0 1572864          // l1: MROWS*64 -> AH/AG
#define PC1 (PC0 + 4096)     // Wb2 (O=32,C=16,Kp=32)
#define PC2 (PC1 + 8192)     // Wb3 (O=64,C=32,Kp=32)
#define PC3 (PC2 + 32768)    // Wb4 (O=128,C=64,Kp=64)
#define PC4 (PC3 + 49152)    // Wc frag-ordered (192 x 256)
#define PC5 (PC4 + 32768)    // Wi1 frag-ordered (256 x 128)
#define PC6 (PC5 + 65536)    // Wi2 interleaved frag-ordered (512 x 128)
#define KNN_BLOCKS (NBP / 4)       // 2048
#define PREP_BLOCKS (PC6 / 256)    // 6896

__global__ __launch_bounds__(256) void prep_knn_kernel(
    const float* __restrict__ x, int* __restrict__ idx,
    __half* __restrict__ AH, float* __restrict__ AG,
    const float* __restrict__ w1f, const float* __restrict__ w1d,
    const float* __restrict__ w2f, const float* __restrict__ w2d,
    unsigned short* __restrict__ Wb2h, unsigned short* __restrict__ Wb2l,
    const float* __restrict__ w3f, const float* __restrict__ w3d,
    unsigned short* __restrict__ Wb3h, unsigned short* __restrict__ Wb3l,
    const float* __restrict__ w4f, const float* __restrict__ w4d,
    unsigned short* __restrict__ Wb4h, unsigned short* __restrict__ Wb4l,
    const float* __restrict__ wcf, const float* __restrict__ wcd,
    unsigned short* __restrict__ Wch, unsigned short* __restrict__ Wcl,
    const float* __restrict__ wi1f, const float* __restrict__ wi1d,
    unsigned short* __restrict__ Wi1h, unsigned short* __restrict__ Wi1l,
    const float* __restrict__ wi2f, const float* __restrict__ wi2d,
    unsigned short* __restrict__ Wi2h, unsigned short* __restrict__ Wi2l)
{
    __shared__ unsigned ksh[4][64 * 34];
    if (blockIdx.x < KNN_BLOCKS) {
        // ---- KNN: one query per wave, keys in this wave's LDS slice ----
        const int t  = threadIdx.x & 63;
        const int wq = threadIdx.x >> 6;
        const int bn = blockIdx.x * 4 + wq;
        const int b = bn >> 11;
        const int n = bn & (NPTS - 1);
        const float* xb = x + b * 3 * NPTS;
        const float qx = xb[n], qy = xb[NPTS + n], qz = xb[2 * NPTS + n];
        const float sqn = fmaf(qz, qz, fmaf(qy, qy, qx * qx));
        unsigned* ks = &ksh[wq][t * 34];

        unsigned gm[4];
        int ga[4];
#pragma unroll
        for (int g = 0; g < 4; g++) {
            unsigned kk[8];
#pragma unroll
            for (int j = 0; j < 8; j++) {
                const int i = g * 8 + j;
                const int m = (i << 6) + t;
                float mx = xb[m], my = xb[NPTS + m], mz = xb[2 * NPTS + m];
                float sqm = fmaf(mz, mz, fmaf(my, my, mx * mx));
                float dt  = fmaf(qz, mz, fmaf(qy, my, qx * mx));
                float d2  = sqn + sqm - 2.0f * dt;
                unsigned u = __float_as_uint(d2);
                u ^= (u & 0x80000000u) ? 0xFFFFFFFFu : 0x80000000u;  // monotone map
                kk[j] = u;
            }
            *(uint2*)&ks[g * 8 + 0] = make_uint2(kk[0], kk[1]);
            *(uint2*)&ks[g * 8 + 2] = make_uint2(kk[2], kk[3]);
            *(uint2*)&ks[g * 8 + 4] = make_uint2(kk[4], kk[5]);
            *(uint2*)&ks[g * 8 + 6] = make_uint2(kk[6], kk[7]);
            unsigned bg = kk[0];
            int ba = g * 8;
#pragma unroll
            for (int j = 1; j < 8; j++) {
                if (kk[j] < bg) { bg = kk[j]; ba = g * 8 + j; }
            }
            gm[g] = bg; ga[g] = ba;
        }
        unsigned lm = gm[0];
        int il = ga[0];
#pragma unroll
        for (int g = 1; g < 4; g++) if (gm[g] < lm) { lm = gm[g]; il = ga[g]; }

        unsigned long long pk = ((unsigned long long)lm << 32) | (unsigned)((il << 6) | t);
        int res = -1;
        for (int r = 0; r < KNN_K; r++) {
            unsigned long long w = pk;
#pragma unroll
            for (int off = 32; off > 0; off >>= 1) {
                unsigned long long o = shfl_xor_u64(w, off);
                w = (o < w) ? o : w;
            }
            if (t == r) res = (int)(w & 0xFFFFFFFFull);

            if (pk == w) {                    // exactly one owner lane (m unique)
                ks[il] = 0xFFFFFFFFu;
                const int g = il >> 3;
                unsigned bg = ks[g * 8];
                int ba = g * 8;
#pragma unroll
                for (int j = 1; j < 8; j++) {
                    unsigned kv = ks[g * 8 + j];
                    if (kv < bg) { bg = kv; ba = g * 8 + j; }
                }
                gm[g] = bg; ga[g] = ba;
                lm = gm[0]; il = ga[0];
#pragma unroll
                for (int g2 = 1; g2 < 4; g2++) if (gm[g2] < lm) { lm = gm[g2]; il = ga[g2]; }
                pk = ((unsigned long long)lm << 32) | (unsigned)((il << 6) | t);
            }
        }
        if (t < KNN_K) idx[bn * KNN_K + t] = res;
        return;
    }

    // ---- prep: layer-1 + weight builds ----
    const int i = (blockIdx.x - KNN_BLOCKS) * 256 + threadIdx.x;
    if (i < PC0) {
        int o = i & 63;
        int row = i >> 6;
        int v = row % 3;
        int gp = row / 3;
        int b = gp >> 11;
        int n = gp & (NPTS - 1);
        float xv = x[(b * 3 + v) * NPTS + n];
        float wv = wbig_val(w1f, w1d, o, 0, 16, 1);
        float val = xv * wv;
        if (o < 32) AH[(size_t)row * 32 + o] = __float2half(val);
        else        AG[(size_t)row * 32 + o - 32] = val;
    } else if (i < PC6) {
        float v = 0.f;
        unsigned short *ph, *pl;
        int ix;
        if (i < PC1) {            // Wb2: O=32,C=16,Kpad=32
            ix = i - PC0;
            int c = ix & 31, j = ix >> 5;
            if (c < 16) v = wbig_val(w2f, w2d, j, c, 32, 16);
            ph = Wb2h; pl = Wb2l;
        } else if (i < PC2) {     // Wb3: O=64,C=32,Kpad=32
            ix = i - PC1;
            int c = ix & 31, j = ix >> 5;
            v = wbig_val(w3f, w3d, j, c, 64, 32);
            ph = Wb3h; pl = Wb3l;
        } else if (i < PC3) {     // Wb4: O=128,C=64,Kpad=64
            ix = i - PC2;
            int c = ix & 63, j = ix >> 6;
            v = wbig_val(w4f, w4d, j, c, 128, 64);
            ph = Wb4h; pl = Wb4l;
        } else if (i < PC4) {     // Wc frag-ordered: 192 rows x 256 k (RB=12)
            ix = i - PC3;
            int c = ix & 255, r = ix >> 8;
            if (c < 240) {
                if (r < 128) v = wcf[r * 240 + c];
                else if (r < 129) v = wcd[(r - 128) * 240 + c];
            }
            ph = Wch; pl = Wcl;
            ix = frag_ix(r, c, 12);
        } else if (i < PC5) {     // Wi1 frag-ordered: 256 rows x 128 k (RB=16)
            ix = i - PC4;
            int c = ix & 127, r = ix >> 7;
            if (r < 128) v = wi1f[r * 256 + c];
            else v = wi1d[(r - 128) * 256 + c];
            ph = Wi1h; pl = Wi1l;
            ix = frag_ix(r, c, 16);
        } else {                  // Wi2 interleaved rows (2o=f,2o+1=d), frag-ordered (RB=32)
            ix = i - PC5;
            int c = ix & 127, r = ix >> 7;
            int o = r >> 1;
            v = (r & 1) ? wi2d[o * 128 + c] : wi2f[o * 128 + c];
            ph = Wi2h; pl = Wi2l;
            ix = frag_ix(r, c, 32);
        }
        unsigned short h, l;
        split_bf16(v, h, l);
        ph[ix] = h; pl[ix] = l;
    }
}

// ---------------------------------------------------------------------------
// Fused edge + gemm (layers 2 and 3). Block = 16 points (48 rows), 4 waves.
// ---------------------------------------------------------------------------
template <int OIN, int NF>
__global__ __launch_bounds__(256, 3) void edge_gemm_kernel(
    const __half* __restrict__ AHin, const float* __restrict__ AGin,
    const int* __restrict__ idx,
    unsigned short* __restrict__ X240h, unsigned short* __restrict__ X240l, int ooff,
    const unsigned short* __restrict__ Wh, const unsigned short* __restrict__ Wl,
    __half* __restrict__ OUTA, float* __restrict__ OUTG)
{
    constexpr int PTS = 16;
    constexpr int NC = NF * 64;        // gemm output cols (2*twoO_out)
    constexpr int twoO = NC / 2;
    constexpr int LDW = 40;            // W LDS row stride (u16)
    constexpr int CPT = OIN / 16;      // channels per thread: 1 (O=16) or 2 (O=32)
    constexpr int twoOin = 2 * OIN;

    __shared__ unsigned short Xsh[48][32];
    __shared__ unsigned short Xsl[48][32];
    __shared__ unsigned short wbh[NC][LDW];
    __shared__ unsigned short wbl[NC][LDW];
    __shared__ int sIdx[PTS][KNN_K];

    const int lb = xcd_swizzle(blockIdx.x, gridDim.x);
    const int tid = threadIdx.x;

    // stage W + idx (W has no dependence on edge outputs)
    for (int rr = tid; rr < NC; rr += 256) {
#pragma unroll
        for (int scc = 0; scc < 4; scc++) {
            *(uint4*)&wbh[rr][scc * 8] = *(const uint4*)(Wh + (size_t)rr * 32 + scc * 8);
            *(uint4*)&wbl[rr][scc * 8] = *(const uint4*)(Wl + (size_t)rr * 32 + scc * 8);
        }
    }
    for (int j = tid; j < PTS * KNN_K; j += 256)
        sIdx[j >> 4][j & 15] = idx[(lb * PTS + (j >> 4)) * KNN_K + (j & 15)];
    __syncthreads();

    // ---- edge phase: 16 threads per point, CPT channels per thread ----
    const int op = tid & 15;
    const int pt = tid >> 4;
    const int gp = lb * PTS + pt;
    const int b = gp >> 11;
    const int rown = gp * 3;
    const int bbase = (b << 11) * 3;

    float cg[3][2 * CPT];
#pragma unroll
    for (int v = 0; v < 3; v++) {
        if constexpr (CPT == 2) {
            float4 c4 = *(const float4*)&AGin[(size_t)(rown + v) * twoOin + 4 * op];
            cg[v][0] = c4.x; cg[v][1] = c4.y; cg[v][2] = c4.z; cg[v][3] = c4.w;
        } else {
            float2 c2 = *(const float2*)&AGin[(size_t)(rown + v) * twoOin + 2 * op];
            cg[v][0] = c2.x; cg[v][1] = c2.y;
        }
    }
    float am[CPT][3];
#pragma unroll
    for (int c0 = 0; c0 < CPT; c0++) { am[c0][0] = 0.f; am[c0][1] = 0.f; am[c0][2] = 0.f; }

#pragma unroll 2
    for (int k = 0; k < KNN_K; k++) {
        const int m = sIdx[pt][k];
        const __half* base = AHin + (size_t)(bbase + m * 3) * twoOin + 2 * CPT * op;
        float e[3][2 * CPT];
#pragma unroll
        for (int v = 0; v < 3; v++) {
            if constexpr (CPT == 2) {
                uint2 u = *(const uint2*)(base + (size_t)v * twoOin);
                float2 x0 = __half22float2(*(__half2*)&u.x);
                float2 x1 = __half22float2(*(__half2*)&u.y);
                e[v][0] = x0.x; e[v][1] = x0.y; e[v][2] = x1.x; e[v][3] = x1.y;
            } else {
                unsigned u = *(const unsigned*)(base + (size_t)v * twoOin);
                float2 x0 = __half22float2(*(__half2*)&u);
                e[v][0] = x0.x; e[v][1] = x0.y;
            }
        }
#pragma unroll
        for (int c0 = 0; c0 < CPT; c0++) {
            float p0 = e[0][2 * c0] + cg[0][2 * c0], d0 = e[0][2 * c0 + 1] + cg[0][2 * c0 + 1];
            float p1 = e[1][2 * c0] + cg[1][2 * c0], d1 = e[1][2 * c0 + 1] + cg[1][2 * c0 + 1];
            float p2 = e[2][2 * c0] + cg[2][2 * c0], d2 = e[2][2 * c0 + 1] + cg[2][2 * c0 + 1];
            float dot = fmaf(p2, d2, fmaf(p1, d1, p0 * d0));
            float dsq = fmaf(d2, d2, fmaf(d1, d1, d0 * d0));
            float s = lna_scale(dot, dsq);
            am[c0][0] += fmaf(-s, d0, p0);
            am[c0][1] += fmaf(-s, d1, p1);
            am[c0][2] += fmaf(-s, d2, p2);
        }
    }

    // mean, write-through to X240, stage split-bf16 A-tile in LDS
#pragma unroll
    for (int v = 0; v < 3; v++) {
#pragma unroll
        for (int c0 = 0; c0 < CPT; c0++) {
            const int ch = CPT * op + c0;
            unsigned short h, l;
            split_bf16(am[c0][v] * 0.0625f, h, l);
            Xsh[pt * 3 + v][ch] = h;
            Xsl[pt * 3 + v][ch] = l;
            const size_t ob = (size_t)(rown + v) * 256 + ooff + ch;
            X240h[ob] = h; X240l[ob] = l;
        }
        if constexpr (CPT == 1) {      // zero-pad k = 16..32
            Xsh[pt * 3 + v][16 + op] = 0;
            Xsl[pt * 3 + v][16 + op] = 0;
        }
    }
    __syncthreads();

    // ---- gemm phase: one K-step (Kpad=32), waves split N ----
    const int lane = tid & 63;
    const int wv = tid >> 6;
    const int mr = lane & 15;
    const int q  = lane >> 4;

    f32x4 acc[3][NF];
#pragma unroll
    for (int a = 0; a < 3; a++)
#pragma unroll
        for (int c = 0; c < NF; c++) acc[a][c] = (f32x4){0.f, 0.f, 0.f, 0.f};

    bf16x8 ah[3], al[3], bh[NF], bl[NF];
#pragma unroll
    for (int mf = 0; mf < 3; mf++) {
        ah[mf] = *(const bf16x8*)&Xsh[mf * 16 + mr][q * 8];
        al[mf] = *(const bf16x8*)&Xsl[mf * 16 + mr][q * 8];
    }
#pragma unroll
    for (int nf = 0; nf < NF; nf++) {
        const int wr = wv * 16 * NF + nf * 16 + mr;
        bh[nf] = *(const bf16x8*)&wbh[wr][q * 8];
        bl[nf] = *(const bf16x8*)&wbl[wr][q * 8];
    }
#pragma unroll
    for (int mf = 0; mf < 3; mf++)
#pragma unroll
        for (int nf = 0; nf < NF; nf++) {
            acc[mf][nf] = __builtin_amdgcn_mfma_f32_16x16x32_bf16(ah[mf], bh[nf], acc[mf][nf], 0, 0, 0);
            acc[mf][nf] = __builtin_amdgcn_mfma_f32_16x16x32_bf16(ah[mf], bl[nf], acc[mf][nf], 0, 0, 0);
            acc[mf][nf] = __builtin_amdgcn_mfma_f32_16x16x32_bf16(al[mf], bh[nf], acc[mf][nf], 0, 0, 0);
        }

    // epilogue: col split AH (fp16) / AG (fp32) is wave-uniform
    const int rbase = lb * 48;
#pragma unroll
    for (int nf = 0; nf < NF; nf++) {
        const int col = wv * 16 * NF + nf * 16 + mr;
#pragma unroll
        for (int mf = 0; mf < 3; mf++)
#pragma unroll
            for (int i = 0; i < 4; i++) {
                const int row = rbase + mf * 16 + q * 4 + i;
                const float val = acc[mf][nf][i];
                if (col < twoO) OUTA[(size_t)row * twoO + col] = __float2half(val);
                else            OUTG[(size_t)row * twoO + col - twoO] = val;
            }
    }
}

// ---------------------------------------------------------------------------
// Split-bf16 MFMA GEMM (NT), layer 4 only. Epilogue: col<twoO -> fp16 OUTA;
// else fp32 OUTG.
// ---------------------------------------------------------------------------
__global__ __launch_bounds__(256) void gemm_mfma(
    const unsigned short* __restrict__ Xh, const unsigned short* __restrict__ Xl,
    int ldx, int xoff,
    const unsigned short* __restrict__ Wh, const unsigned short* __restrict__ Wl,
    float* __restrict__ OUT, int ldo, int Nout, int Kpad,
    __half* __restrict__ OUTA, float* __restrict__ OUTG, int twoO)
{
    __shared__ unsigned short Ws[2][64][56];
    const int tid = threadIdx.x;
    const int bm = blockIdx.x * 256;
    const int bo = blockIdx.y * 64;
    const int lane = tid & 63;
    const int wv = tid >> 6;
    const int mr = lane & 15;
    const int q  = lane >> 4;

    f32x4 acc[4][4];
#pragma unroll
    for (int a = 0; a < 4; a++)
#pragma unroll
        for (int c = 0; c < 4; c++) acc[a][c] = (f32x4){0.f, 0.f, 0.f, 0.f};

    const int wr = tid >> 2;   // 0..63
    const int sc = tid & 3;    // k-chunk 0..3

    for (int k0 = 0; k0 < Kpad; k0 += 32) {
        {
            const uint4 vh = *(const uint4*)(Wh + (size_t)(bo + wr) * Kpad + k0 + sc * 8);
            const uint4 vl = *(const uint4*)(Wl + (size_t)(bo + wr) * Kpad + k0 + sc * 8);
            *(uint4*)&Ws[0][wr][sc * 8] = vh;
            *(uint4*)&Ws[1][wr][sc * 8] = vl;
        }
        __syncthreads();

        bf16x8 ah[4], al[4], bh[4], bl[4];
#pragma unroll
        for (int mf = 0; mf < 4; mf++) {
            const size_t xrow = (size_t)(bm + wv * 64 + mf * 16 + mr) * ldx + xoff + k0 + q * 8;
            ah[mf] = *(const bf16x8*)(Xh + xrow);
            al[mf] = *(const bf16x8*)(Xl + xrow);
        }
#pragma unroll
        for (int nf = 0; nf < 4; nf++) {
            bh[nf] = *(const bf16x8*)&Ws[0][nf * 16 + mr][q * 8];
            bl[nf] = *(const bf16x8*)&Ws[1][nf * 16 + mr][q * 8];
        }
#pragma unroll
        for (int mf = 0; mf < 4; mf++)
#pragma unroll
            for (int nf = 0; nf < 4; nf++) {
                acc[mf][nf] = __builtin_amdgcn_mfma_f32_16x16x32_bf16(ah[mf], bh[nf], acc[mf][nf], 0, 0, 0);
                acc[mf][nf] = __builtin_amdgcn_mfma_f32_16x16x32_bf16(ah[mf], bl[nf], acc[mf][nf], 0, 0, 0);
                acc[mf][nf] = __builtin_amdgcn_mfma_f32_16x16x32_bf16(al[mf], bh[nf], acc[mf][nf], 0, 0, 0);
            }
        __syncthreads();
    }

    // epilogue: D layout col=lane&15, row=q*4+i
    if (OUTA) {
#pragma unroll
        for (int nf = 0; nf < 4; nf++) {
            const int col = bo + nf * 16 + mr;
            if (col < twoO) {
#pragma unroll
                for (int mf = 0; mf < 4; mf++)
#pragma unroll
                    for (int i = 0; i < 4; i++) {
                        const int row = bm + wv * 64 + mf * 16 + q * 4 + i;
                        OUTA[(size_t)row * twoO + col] = __float2half(acc[mf][nf][i]);
                    }
            } else {
#pragma unroll
                for (int mf = 0; mf < 4; mf++)
#pragma unroll
                    for (int i = 0; i < 4; i++) {
                        const int row = bm + wv * 64 + mf * 16 + q * 4 + i;
                        OUTG[(size_t)row * twoO + col - twoO] = acc[mf][nf][i];
                    }
            }
        }
    } else {
#pragma unroll
        for (int nf = 0; nf < 4; nf++) {
            const int col = bo + nf * 16 + mr;
            if (col < Nout) {
#pragma unroll
                for (int mf = 0; mf < 4; mf++)
#pragma unroll
                    for (int i = 0; i < 4; i++) {
                        const int row = bm + wv * 64 + mf * 16 + q * 4 + i;
                        OUT[(size_t)row * ldo + col] = acc[mf][nf][i];
                    }
            }
        }
    }
}

// ---------------------------------------------------------------------------
// Edge conv + vec_lna + mean over K neighbors -> bf16 hi/lo output (ld 256).
// Only layer-3 edge (O=64) remains a standalone dispatch.
// ---------------------------------------------------------------------------
template <int O, int PT>
__global__ __launch_bounds__(256, 6) void edge_kernel(const __half* __restrict__ AH,
                                                      const float* __restrict__ AG,
                                                      const int* __restrict__ idx,
                                                      unsigned short* __restrict__ outh,
                                                      unsigned short* __restrict__ outl,
                                                      int ooff)
{
    constexpr int TP = O / 2;          // threads per point
    constexpr int twoO = 2 * O;
    const int lb = xcd_swizzle(blockIdx.x, gridDim.x);
    const int tid = threadIdx.x;
    const int op = tid % TP;
    const int pt = tid / TP;
    const int gp = lb * PT + pt;
    const int b = gp >> 11;
    __shared__ int sIdx[PT][KNN_K];
    for (int j = tid; j < PT * KNN_K; j += 256)
        sIdx[j >> 4][j & 15] = idx[(lb * PT + (j >> 4)) * KNN_K + (j & 15)];
    __syncthreads();
    const int rown = gp * 3;
    const float4 c0 = *(const float4*)&AG[(size_t)(rown + 0) * twoO + 4 * op];
    const float4 c1 = *(const float4*)&AG[(size_t)(rown + 1) * twoO + 4 * op];
    const float4 c2 = *(const float4*)&AG[(size_t)(rown + 2) * twoO + 4 * op];
    float ax0 = 0.f, ax1 = 0.f, ax2 = 0.f;   // o = 2op
    float ay0 = 0.f, ay1 = 0.f, ay2 = 0.f;   // o = 2op+1
    const int bbase = (b << 11) * 3;
#pragma unroll 2
    for (int k = 0; k < KNN_K; k++) {
        int m = sIdx[pt][k];
        const __half* base = AH + (size_t)(bbase + m * 3) * twoO + 4 * op;
        uint2 u0 = *(const uint2*)(base);
        uint2 u1 = *(const uint2*)(base + twoO);
        uint2 u2 = *(const uint2*)(base + 2 * twoO);
        float2 e0 = __half22float2(*(__half2*)&u0.x);
        float2 f0 = __half22float2(*(__half2*)&u0.y);
        float2 e1 = __half22float2(*(__half2*)&u1.x);
        float2 f1 = __half22float2(*(__half2*)&u1.y);
        float2 e2 = __half22float2(*(__half2*)&u2.x);
        float2 f2 = __half22float2(*(__half2*)&u2.y);
        {
            float p0 = e0.x + c0.x, d0 = e0.y + c0.y;
            float p1 = e1.x + c1.x, d1 = e1.y + c1.y;
            float p2 = e2.x + c2.x, d2 = e2.y + c2.y;
            float dot = fmaf(p2, d2, fmaf(p1, d1, p0 * d0));
            float dsq = fmaf(d2, d2, fmaf(d1, d1, d0 * d0));
            float s = lna_scale(dot, dsq);
            ax0 += fmaf(-s, d0, p0);
            ax1 += fmaf(-s, d1, p1);
            ax2 += fmaf(-s, d2, p2);
        }
        {
            float p0 = f0.x + c0.z, d0 = f0.y + c0.w;
            float p1 = f1.x + c1.z, d1 = f1.y + c1.w;
            float p2 = f2.x + c2.z, d2 = f2.y + c2.w;
            float dot = fmaf(p2, d2, fmaf(p1, d1, p0 * d0));
            float dsq = fmaf(d2, d2, fmaf(d1, d1, d0 * d0));
            float s = lna_scale(dot, dsq);
            ay0 += fmaf(-s, d0, p0);
            ay1 += fmaf(-s, d1, p1);
            ay2 += fmaf(-s, d2, p2);
        }
    }
    float rx[3] = { ax0 * 0.0625f, ax1 * 0.0625f, ax2 * 0.0625f };
    float ry[3] = { ay0 * 0.0625f, ay1 * 0.0625f, ay2 * 0.0625f };
#pragma unroll
    for (int v = 0; v < 3; v++) {
        unsigned short hx, lx, hy, ly;
        split_bf16(rx[v], hx, lx);
        split_bf16(ry[v], hy, ly);
        const size_t ob = (size_t)(rown + v) * 256 + ooff + 2 * op;
        *(unsigned*)(outh + ob) = (unsigned)hx | ((unsigned)hy << 16);
        *(unsigned*)(outl + ob) = (unsigned)lx | ((unsigned)ly << 16);
    }
}

// ---------------------------------------------------------------------------
// Fused layer-4 edge (O=128) + wc GEMM + lna. Block = 16 points.
// Wc B-frags read via frag-order (coalesced); tb unions the x4 LDS region.
// ---------------------------------------------------------------------------
#define EW_LDX 136   // x4 u16 stride
#define EW_LDT 133   // tb fp32 stride
__global__ __launch_bounds__(256, 4) void edge_wc_kernel(
    const __half* __restrict__ AHin, const float* __restrict__ AGin,   // ld 256
    const int* __restrict__ idx,
    const unsigned short* __restrict__ Xh, const unsigned short* __restrict__ Xl, // X240 ld 256 (cols 0..111)
    const unsigned short* __restrict__ Wh, const unsigned short* __restrict__ Wl, // Wc frag-ordered 192x256
    unsigned short* __restrict__ oh, unsigned short* __restrict__ ol,  // xc2 ld 128
    float* __restrict__ part2)
{
    // union: x4h(13056) + x4l(13056) = 26112B; tb needs 48*133*4 = 25536B
    __shared__ __align__(16) char smem[48 * EW_LDX * 2 * 2];
    unsigned short (*x4h)[EW_LDX] = (unsigned short (*)[EW_LDX])smem;
    unsigned short (*x4l)[EW_LDX] = (unsigned short (*)[EW_LDX])(smem + 48 * EW_LDX * 2);
    float* tb = (float*)smem;
    __shared__ int sIdx[16][KNN_K];

    const int lb = xcd_swizzle(blockIdx.x, gridDim.x);
    const int tid = threadIdx.x;

    for (int j = tid; j < 16 * KNN_K; j += 256)
        sIdx[j >> 4][j & 15] = idx[(lb * 16 + (j >> 4)) * KNN_K + (j & 15)];
    __syncthreads();

    // ---- edge phase: 16 thr/pt, 8 channels/thr ----
    {
        const int op = tid & 15;
        const int pt = tid >> 4;
        const int gp = lb * 16 + pt;
        const int b = gp >> 11;
        const int rown = gp * 3;
        const int bbase = (b << 11) * 3;

        float cg[3][16];
#pragma unroll
        for (int v = 0; v < 3; v++) {
            const float* ag = &AGin[(size_t)(rown + v) * 256 + 16 * op];
#pragma unroll
            for (int t = 0; t < 4; t++) {
                float4 c4 = *(const float4*)(ag + 4 * t);
                cg[v][4 * t + 0] = c4.x; cg[v][4 * t + 1] = c4.y;
                cg[v][4 * t + 2] = c4.z; cg[v][4 * t + 3] = c4.w;
            }
        }
        float am[8][3];
#pragma unroll
        for (int c0 = 0; c0 < 8; c0++) { am[c0][0] = 0.f; am[c0][1] = 0.f; am[c0][2] = 0.f; }

        for (int k = 0; k < KNN_K; k++) {
            const int m = sIdx[pt][k];
            const __half* base = AHin + (size_t)(bbase + m * 3) * 256 + 16 * op;
            unsigned uw[3][8];
#pragma unroll
            for (int v = 0; v < 3; v++) {
                uint4 a  = *(const uint4*)(base + (size_t)v * 256);
                uint4 bq = *(const uint4*)(base + (size_t)v * 256 + 8);
                uw[v][0] = a.x;  uw[v][1] = a.y;  uw[v][2] = a.z;  uw[v][3] = a.w;
                uw[v][4] = bq.x; uw[v][5] = bq.y; uw[v][6] = bq.z; uw[v][7] = bq.w;
            }
#pragma unroll
            for (int c0 = 0; c0 < 8; c0++) {
                float2 e0 = __half22float2(*(__half2*)&uw[0][c0]);
                float2 e1 = __half22float2(*(__half2*)&uw[1][c0]);
                float2 e2 = __half22float2(*(__half2*)&uw[2][c0]);
                float p0 = e0.x + cg[0][2 * c0], d0 = e0.y + cg[0][2 * c0 + 1];
                float p1 = e1.x + cg[1][2 * c0], d1 = e1.y + cg[1][2 * c0 + 1];
                float p2 = e2.x + cg[2][2 * c0], d2 = e2.y + cg[2][2 * c0 + 1];
                float dot = fmaf(p2, d2, fmaf(p1, d1, p0 * d0));
                float dsq = fmaf(d2, d2, fmaf(d1, d1, d0 * d0));
                float s = lna_scale(dot, dsq);
                am[c0][0] += fmaf(-s, d0, p0);
                am[c0][1] += fmaf(-s, d1, p1);
                am[c0][2] += fmaf(-s, d2, p2);
            }
        }
#pragma unroll
        for (int v = 0; v < 3; v++)
#pragma unroll
            for (int c0 = 0; c0 < 8; c0++) {
                unsigned short h, l;
                split_bf16(am[c0][v] * 0.0625f, h, l);
                x4h[pt * 3 + v][8 * op + c0] = h;
                x4l[pt * 3 + v][8 * op + c0] = l;
            }
    }
    __syncthreads();

    // ---- wc GEMM: K=256 pad, A source select, B frag-ordered from global ----
    const int lane = tid & 63;
    const int wv = tid >> 6;
    const int mr = lane & 15;
    const int q  = lane >> 4;
    const int rbase = lb * 48;

    f32x4 acc[3][3];
#pragma unroll
    for (int a = 0; a < 3; a++)
#pragma unroll
        for (int c = 0; c < 3; c++) acc[a][c] = (f32x4){0.f, 0.f, 0.f, 0.f};

    for (int k0 = 0; k0 < 256; k0 += 32) {
        const int kb = k0 + q * 8;
        bf16x8 ah[3], al[3], bh[3], bl[3];
#pragma unroll
        for (int mf = 0; mf < 3; mf++) {
            const int row = mf * 16 + mr;
            if (kb >= 112) {
                if (kb >= 240) {
                    ah[mf] = (bf16x8){0, 0, 0, 0, 0, 0, 0, 0};
                    al[mf] = (bf16x8){0, 0, 0, 0, 0, 0, 0, 0};
                } else {
                    ah[mf] = *(const bf16x8*)&x4h[row][kb - 112];
                    al[mf] = *(const bf16x8*)&x4l[row][kb - 112];
                }
            } else {
                const size_t xr = (size_t)(rbase + row) * 256 + kb;
                ah[mf] = *(const bf16x8*)(Xh + xr);
                al[mf] = *(const bf16x8*)(Xl + xr);
            }
        }
#pragma unroll
        for (int nf = 0; nf < 3; nf++) {
            const size_t wri = (size_t)((((k0 >> 5) * 12) + wv * 3 + nf) * 64 + lane) * 8;
            bh[nf] = *(const bf16x8*)(Wh + wri);
            bl[nf] = *(const bf16x8*)(Wl + wri);
        }
#pragma unroll
        for (int mf = 0; mf < 3; mf++)
#pragma unroll
            for (int nf = 0; nf < 3; nf++) {
                acc[mf][nf] = __builtin_amdgcn_mfma_f32_16x16x32_bf16(ah[mf], bh[nf], acc[mf][nf], 0, 0, 0);
                acc[mf][nf] = __builtin_amdgcn_mfma_f32_16x16x32_bf16(ah[mf], bl[nf], acc[mf][nf], 0, 0, 0);
                acc[mf][nf] = __builtin_amdgcn_mfma_f32_16x16x32_bf16(al[mf], bh[nf], acc[mf][nf], 0, 0, 0);
            }
    }
    __syncthreads();   // x4 dead; tb overlays it

    // stage cols 0..128 (p cols + shared d col)
#pragma unroll
    for (int mf = 0; mf < 3; mf++)
#pragma unroll
        for (int nf = 0; nf < 3; nf++) {
            const int col = wv * 48 + nf * 16 + mr;
            if (col <= 128) {
#pragma unroll
                for (int i = 0; i < 4; i++)
                    tb[(mf * 16 + q * 4 + i) * EW_LDT + col] = acc[mf][nf][i];
            }
        }
    __syncthreads();

    const int bp0 = lb * 16;
    float vacc[3] = {0.f, 0.f, 0.f};
#pragma unroll
    for (int it = 0; it < 8; it++) {
        const int item = it * 256 + tid;   // 2048 = 16 pts x 128 o
        const int o = item & 127;
        const int pt = item >> 7;
        float p[3], d[3];
#pragma unroll
        for (int v = 0; v < 3; v++) {
            const int r = pt * 3 + v;
            p[v] = tb[r * EW_LDT + o];
            d[v] = tb[r * EW_LDT + 128];
        }
        float dot = fmaf(p[2], d[2], fmaf(p[1], d[1], p[0] * d[0]));
        float dsq = fmaf(d[2], d[2], fmaf(d[1], d[1], d[0] * d[0]));
        float s = lna_scale(dot, dsq);
#pragma unroll
        for (int v = 0; v < 3; v++) {
            float val = fmaf(-s, d[v], p[v]);
            vacc[v] += val;
            unsigned short h, l;
            split_bf16(val, h, l);
            const size_t ob = ((size_t)(bp0 + pt) * 3 + v) * 128 + o;
            oh[ob] = h; ol[ob] = l;
        }
    }

    __syncthreads();
    tb[tid] = vacc[0]; tb[256 + tid] = vacc[1]; tb[512 + tid] = vacc[2];
    __syncthreads();
    if (tid < 128) {
#pragma unroll
        for (int v = 0; v < 3; v++)
            part2[(size_t)lb * 384 + v * 128 + tid] =
                tb[v * 256 + tid] + tb[v * 256 + tid + 128];
    }
}

// ---------------------------------------------------------------------------
// xm reduce + ym: part2[512][3][128] -> xm (bf16-pair, 12x128) AND
// ym[12][256] = xm @ Wi1stack[:,128:256]^T (constant K>=128 part of wi1).
// ---------------------------------------------------------------------------
__global__ __launch_bounds__(128) void xm_reduce_ym_kernel(
    const float* __restrict__ part2,
    unsigned short* __restrict__ xmh, unsigned short* __restrict__ xml,
    const float* __restrict__ wi1f, const float* __restrict__ wi1d,
    float* __restrict__ ym)
{
    __shared__ float xs[128];
    const int bv = blockIdx.x;       // 12 = b*3+v
    const int b = bv / 3;
    const int v = bv % 3;
    const int o = threadIdx.x;       // 128
    float acc = 0.f;
    for (int i = 0; i < 128; i++)
        acc += part2[(size_t)(b * 128 + i) * 384 + v * 128 + o];
    const float m = acc * (1.f / 2048.f);
    unsigned short h, l;
    split_bf16(m, h, l);
    xmh[bv * 128 + o] = h;
    xml[bv * 128 + o] = l;
    xs[o] = m;
    __syncthreads();
#pragma unroll
    for (int half = 0; half < 2; half++) {
        const int oo = half * 128 + o;
        const float* wrow = (oo < 128) ? (wi1f + (size_t)oo * 256 + 128)
                                       : (wi1d + (size_t)(oo - 128) * 256 + 128);
        float s = 0.f;
        for (int c = 0; c < 128; c++) s = fmaf(wrow[c], xs[c], s);
        ym[(size_t)bv * 256 + oo] = s;
    }
}

// ---------------------------------------------------------------------------
// Fused wi1 + wi2 + inv (R16 structure). R18: phase-1 B loads direct from
// frag-ordered global Wi1 (256x128, RB=16) -- removes the wb LDS staging and
// ALL K-loop barriers. tb epilogue / y1 LDS / phase 2 unchanged from R16.
// ---------------------------------------------------------------------------
#define QI_LDY  136    // y1 u16 stride
#define QI_LDT  257    // phase-1 tb fp32 stride
#define QI_LDT2 67     // phase-2 per-wave tile fp32 stride
__global__ __launch_bounds__(256, 2) void gemm_ii_kernel(
    const unsigned short* __restrict__ xch, const unsigned short* __restrict__ xcl, // ld 128
    const unsigned short* __restrict__ W1h, const unsigned short* __restrict__ W1l, // Wi1 frag 256x128
    const unsigned short* __restrict__ W2h, const unsigned short* __restrict__ W2l, // Wi2 frag 512x128 (ilv)
    const unsigned short* __restrict__ xmh, const unsigned short* __restrict__ xml,
    const float* __restrict__ ym,
    float* __restrict__ out)
{
    __shared__ __align__(16) char regA[51456];   // union: tb(49344) / wt(51456)
    __shared__ __align__(16) unsigned short y1h[48][QI_LDY];
    __shared__ __align__(16) unsigned short y1l[48][QI_LDY];
    float* tb = (float*)regA;

    const int tid = threadIdx.x;
    const int lane = tid & 63;
    const int wv = tid >> 6;
    const int mr = lane & 15;
    const int q  = lane >> 4;
    const int lb = blockIdx.x;
    const int bm = lb * 48;
    const int bb = (lb * 16) >> 11;   // batch (uniform: 16 | 2048)

    // ---- phase 1: wi1 GEMM (N=256, K=128), B direct frag-ordered global ----
    f32x4 acc[3][4];
#pragma unroll
    for (int a = 0; a < 3; a++)
#pragma unroll
        for (int c = 0; c < 4; c++) acc[a][c] = (f32x4){0.f, 0.f, 0.f, 0.f};

    for (int k0 = 0; k0 < 128; k0 += 32) {
        bf16x8 ah[3], al[3];
#pragma unroll
        for (int mf = 0; mf < 3; mf++) {
            const size_t xr = (size_t)(bm + mf * 16 + mr) * 128 + k0 + q * 8;
            ah[mf] = *(const bf16x8*)(xch + xr);
            al[mf] = *(const bf16x8*)(xcl + xr);
        }
        const int ks = k0 >> 5;
#pragma unroll
        for (int nf = 0; nf < 4; nf++) {
            const size_t wi = (size_t)((ks * 16 + wv * 4 + nf) * 64 + lane) * 8;
            const bf16x8 bh = *(const bf16x8*)(W1h + wi);
            const bf16x8 bl = *(const bf16x8*)(W1l + wi);
#pragma unroll
            for (int mf = 0; mf < 3; mf++) {
                acc[mf][nf] = __builtin_amdgcn_mfma_f32_16x16x32_bf16(ah[mf], bh, acc[mf][nf], 0, 0, 0);
                acc[mf][nf] = __builtin_amdgcn_mfma_f32_16x16x32_bf16(ah[mf], bl, acc[mf][nf], 0, 0, 0);
                acc[mf][nf] = __builtin_amdgcn_mfma_f32_16x16x32_bf16(al[mf], bh, acc[mf][nf], 0, 0, 0);
            }
        }
    }

    // stage PD tile: row = mf*16 + q*4 + i, col = wv*64 + nf*16 + mr
#pragma unroll
    for (int mf = 0; mf < 3; mf++)
#pragma unroll
        for (int nf = 0; nf < 4; nf++)
#pragma unroll
            for (int i = 0; i < 4; i++)
                tb[(size_t)(mf * 16 + q * 4 + i) * QI_LDT + wv * 64 + nf * 16 + mr] = acc[mf][nf][i];
    __syncthreads();

    // epilogue 1: lna(+ym) -> y1 LDS
    {
        const int oo = tid & 127;
        float ymp[3], ymd[3];
#pragma unroll
        for (int v = 0; v < 3; v++) {
            ymp[v] = ym[(size_t)(bb * 3 + v) * 256 + oo];
            ymd[v] = ym[(size_t)(bb * 3 + v) * 256 + 128 + oo];
        }
#pragma unroll
        for (int it = 0; it < 8; it++) {
            const int item = it * 256 + tid;   // 2048 = 16 pts x 128 o  (o == oo)
            const int o = item & 127;
            const int pt = item >> 7;
            float p[3], d[3];
#pragma unroll
            for (int v = 0; v < 3; v++) {
                const int r = pt * 3 + v;
                p[v] = tb[(size_t)r * QI_LDT + o] + ymp[v];
                d[v] = tb[(size_t)r * QI_LDT + 128 + o] + ymd[v];
            }
            float dot = fmaf(p[2], d[2], fmaf(p[1], d[1], p[0] * d[0]));
            float dsq = fmaf(d[2], d[2], fmaf(d[1], d[1], d[0] * d[0]));
            float s = lna_scale(dot, dsq);
#pragma unroll
            for (int v = 0; v < 3; v++) {
                unsigned short h, l;
                split_bf16(fmaf(-s, d[v], p[v]), h, l);
                y1h[pt * 3 + v][o] = h;
                y1l[pt * 3 + v][o] = l;
            }
        }
    }
    __syncthreads();

    // ---- phase 2: wi2 GEMM (N=512, K=128), A from y1 LDS, B frag-ordered global ----
    f32x4 acc2[3][8];
#pragma unroll
    for (int a = 0; a < 3; a++)
#pragma unroll
        for (int c = 0; c < 8; c++) acc2[a][c] = (f32x4){0.f, 0.f, 0.f, 0.f};

    for (int k0 = 0; k0 < 128; k0 += 32) {
        bf16x8 ah[3], al[3];
#pragma unroll
        for (int mf = 0; mf < 3; mf++) {
            ah[mf] = *(const bf16x8*)&y1h[mf * 16 + mr][k0 + q * 8];
            al[mf] = *(const bf16x8*)&y1l[mf * 16 + mr][k0 + q * 8];
        }
#pragma unroll
        for (int nf = 0; nf < 8; nf++) {
            const size_t wi = (size_t)((((k0 >> 5) * 32) + wv * 8 + nf) * 64 + lane) * 8;
            const bf16x8 bh = *(const bf16x8*)(W2h + wi);
            const bf16x8 bl = *(const bf16x8*)(W2l + wi);
#pragma unroll
            for (int mf = 0; mf < 3; mf++) {
                acc2[mf][nf] = __builtin_amdgcn_mfma_f32_16x16x32_bf16(ah[mf], bh, acc2[mf][nf], 0, 0, 0);
                acc2[mf][nf] = __builtin_amdgcn_mfma_f32_16x16x32_bf16(ah[mf], bl, acc2[mf][nf], 0, 0, 0);
                acc2[mf][nf] = __builtin_amdgcn_mfma_f32_16x16x32_bf16(al[mf], bh, acc2[mf][nf], 0, 0, 0);
            }
        }
    }

    // epilogue 2: per-wave 2-half tile staging -> lna + inv -> out
    float* wt = tb + wv * (48 * QI_LDT2);
#pragma unroll
    for (int hf = 0; hf < 2; hf++) {
        __syncthreads();   // regA reuse fence (uniform)
#pragma unroll
        for (int mf = 0; mf < 3; mf++)
#pragma unroll
            for (int nf2 = 0; nf2 < 4; nf2++)
#pragma unroll
                for (int i = 0; i < 4; i++)
                    wt[(mf * 16 + q * 4 + i) * QI_LDT2 + nf2 * 16 + mr] = acc2[mf][hf * 4 + nf2][i];
#pragma unroll
        for (int j = 0; j < 8; j++) {
            const int item = j * 64 + lane;   // 512 = 16 pts x 32 og-local
            const int ol = item & 31;
            const int pt = item >> 5;
            const int og = wv * 64 + hf * 32 + ol;
            const int gp = lb * 16 + pt;
            float p[3], d[3], xc[3];
#pragma unroll
            for (int v = 0; v < 3; v++) {
                p[v] = wt[(3 * pt + v) * QI_LDT2 + 2 * ol];
                d[v] = wt[(3 * pt + v) * QI_LDT2 + 2 * ol + 1];
                if (og < 128) {
                    const size_t ix = (size_t)(gp * 3 + v) * 128 + og;
                    xc[v] = bf2(xch[ix], xcl[ix]);
                } else {
                    const size_t ix = (size_t)(bb * 3 + v) * 128 + og - 128;
                    xc[v] = bf2(xmh[ix], xml[ix]);
                }
            }
            float dot = fmaf(p[2], d[2], fmaf(p[1], d[1], p[0] * d[0]));
            float dsq = fmaf(d[2], d[2], fmaf(d[1], d[1], d[0] * d[0]));
            float s = lna_scale(dot, dsq);
            float inv = 0.f;
#pragma unroll
            for (int v = 0; v < 3; v++)
                inv = fmaf(xc[v], fmaf(-s, d[v], p[v]), inv);
            out[((size_t)bb * 256 + og) * NPTS + (gp & (NPTS - 1))] = inv;
        }
    }
}

// ---------------------------------------------------------------------------
// launch
// ---------------------------------------------------------------------------
extern "C" void kernel_launch(void* const* d_in, const int* in_sizes, int n_in,
                              void* d_out, int out_size, void* d_ws, size_t ws_size,
                              hipStream_t stream)
{
    const float* x    = (const float*)d_in[0];
    const float* w1f  = (const float*)d_in[1];
    const float* w1d  = (const float*)d_in[2];
    const float* w2f  = (const float*)d_in[3];
    const float* w2d  = (const float*)d_in[4];
    const float* w3f  = (const float*)d_in[5];
    const float* w3d  = (const float*)d_in[6];
    const float* w4f  = (const float*)d_in[7];
    const float* w4d  = (const float*)d_in[8];
    const float* wcf  = (const float*)d_in[9];
    const float* wcd  = (const float*)d_in[10];
    const float* wi1f = (const float*)d_in[11];
    const float* wi1d = (const float*)d_in[12];
    const float* wi2f = (const float*)d_in[13];
    const float* wi2d = (const float*)d_in[14];
    float* out = (float*)d_out;

    float* F = (float*)d_ws;
    size_t off = 0;
    float* AG = F + off;                          off += (size_t)MROWS * 512;  // AG1 = AG, AG2 = AG + MROWS*256
    __half* AH = (__half*)(F + off);              off += (size_t)MROWS * 128;  // AH1
    __half* AH2 = (__half*)(F + off);             off += (size_t)MROWS * 128;  // AH2 (ping-pong)
    unsigned short* X240h = (unsigned short*)(F + off); off += (size_t)MROWS * 128;
    unsigned short* X240l = (unsigned short*)(F + off); off += (size_t)MROWS * 128;
    unsigned short* xc2h  = (unsigned short*)(F + off); off += (size_t)MROWS * 64;  // ld 128
    unsigned short* xc2l  = (unsigned short*)(F + off); off += (size_t)MROWS * 64;
    unsigned short* Wb2h = (unsigned short*)(F + off); off += 2048;
    unsigned short* Wb2l = (unsigned short*)(F + off); off += 2048;
    unsigned short* Wb3h = (unsigned short*)(F + off); off += 4096;
    unsigned short* Wb3l = (unsigned short*)(F + off); off += 4096;
    unsigned short* Wb4h = (unsigned short*)(F + off); off += 16384;
    unsigned short* Wb4l = (unsigned short*)(F + off); off += 16384;
    unsigned short* Wch  = (unsigned short*)(F + off); off += 24576;
    unsigned short* Wcl  = (unsigned short*)(F + off); off += 24576;
    unsigned short* Wi1h = (unsigned short*)(F + off); off += 32768;
    unsigned short* Wi1l = (unsigned short*)(F + off); off += 32768;
    unsigned short* Wi2h = (unsigned short*)(F + off); off += 32768;
    unsigned short* Wi2l = (unsigned short*)(F + off); off += 32768;
    float* part2 = F + off;                       off += (size_t)512 * 384;    // wc per-block sums
    float* ym    = F + off;                       off += 12 * 256;             // wi1 xm-part GEMM
    unsigned short* xmph = (unsigned short*)(F + off); off += 768;   // 12*128 u16
    unsigned short* xmpl = (unsigned short*)(F + off); off += 768;
    int* idx    = (int*)(F + off);                off += NBP * KNN_K;
    float* AG2 = AG + (size_t)MROWS * 256;

    // merged prep (layer-1 + weight builds) + knn
    prep_knn_kernel<<<KNN_BLOCKS + PREP_BLOCKS, 256, 0, stream>>>(
        x, idx, AH, AG, w1f, w1d,
        w2f, w2d, Wb2h, Wb2l, w3f, w3d, Wb3h, Wb3l, w4f, w4d, Wb4h, Wb4l,
        wcf, wcd, Wch, Wcl, wi1f, wi1d, Wi1h, Wi1l, wi2f, wi2d, Wi2h, Wi2l);

    const int GM = MROWS / 256;   // 96

    // layer 1 edge + layer 2 gemm (fused): AH/AG (ld32) -> AH2/AG2 (ld64)
    edge_gemm_kernel<16, 2><<<NBP / 16, 256, 0, stream>>>(
        AH, AG, idx, X240h, X240l, 0, Wb2h, Wb2l, AH2, AG2);
    // layer 2 edge + layer 3 gemm (fused): AH2/AG2 (ld64) -> AH/AG (ld128)
    edge_gemm_kernel<32, 4><<<NBP / 16, 256, 0, stream>>>(
        AH2, AG2, idx, X240h, X240l, 16, Wb3h, Wb3l, AH, AG);
    // layer 3 edge
    edge_kernel<64, 8><<<NBP / 8, 256, 0, stream>>>(AH, AG, idx, X240h, X240l, 48);
    // layer 4: K=64, O=128 -> AH2/AG2 (ld 256)
    gemm_mfma<<<dim3(GM, 8), 256, 0, stream>>>(X240h, X240l, 256, 48, Wb4h, Wb4l, nullptr, 0, 512, 64, AH2, AG2, 256);

    // fused layer-4 edge + wc GEMM + lna -> xc2 + part2 (x4 never hits global)
    edge_wc_kernel<<<NBP / 16, 256, 0, stream>>>(AH2, AG2, idx, X240h, X240l,
                                                 Wch, Wcl, xc2h, xc2l, part2);

    // xm mean + ym precompute (single small dispatch)
    xm_reduce_ym_kernel<<<BATCH * 3, 128, 0, stream>>>(part2, xmph, xmpl, wi1f, wi1d, ym);

    // fused wi1 + wi2 + inv (y1 never hits global)
    gemm_ii_kernel<<<MROWS / 48, 256, 0, stream>>>(xc2h, xc2l, Wi1h, Wi1l,
                                                   Wi2h, Wi2l, xmph, xmpl, ym, out);

    (void)in_sizes; (void)n_in; (void)out_size; (void)ws_size;
}

// Round 9
// 243.652 us; speedup vs baseline: 1.1629x; 1.0342x over previous
//
#include <hip/hip_runtime.h>
#include <hip/hip_fp16.h>

#define NPTS  2048
#define BATCH 4
#define NBP   8192      // BATCH*NPTS
#define MROWS 24576     // NBP*3
#define KNN_K 16

typedef short bf16x8 __attribute__((ext_vector_type(8)));
typedef float f32x4  __attribute__((ext_vector_type(4)));

// split fp32 into bf16 hi + bf16 lo (RTNE), x ~= hi + lo to ~2^-17 rel
static __device__ __forceinline__ void split_bf16(float a, unsigned short& h, unsigned short& l)
{
    unsigned u = __float_as_uint(a);
    unsigned hr = (u + 0x7FFFu + ((u >> 16) & 1u)) & 0xFFFF0000u;
    h = (unsigned short)(hr >> 16);
    float rem = a - __uint_as_float(hr);
    unsigned v = __float_as_uint(rem);
    l = (unsigned short)((v + 0x7FFFu + ((v >> 16) & 1u)) >> 16);
}

static __device__ __forceinline__ float bf2(unsigned short h, unsigned short l)
{
    return __uint_as_float((unsigned)h << 16) + __uint_as_float((unsigned)l << 16);
}

// fast lna scale: s = 0.8*dot/(dsq+eps) via v_rcp_f32 (<=2ulp; tolerance slack huge)
static __device__ __forceinline__ float lna_scale(float dot, float dsq)
{
    return (dot < 0.f) ? 0.8f * dot * __builtin_amdgcn_rcpf(dsq + 1e-6f) : 0.f;
}

static __device__ __forceinline__ unsigned long long shfl_xor_u64(unsigned long long v, int mask)
{
    unsigned lo = (unsigned)v, hi = (unsigned)(v >> 32);
    lo = (unsigned)__shfl_xor((int)lo, mask, 64);
    hi = (unsigned)__shfl_xor((int)hi, mask, 64);
    return ((unsigned long long)hi << 32) | lo;
}

// XCD-confinement swizzle (bijection; wrong mapping assumption = speed-neutral)
static __device__ __forceinline__ int xcd_swizzle(int i, int G)
{
    int batch  = (i >> 1) & 3;
    int within = ((i >> 3) << 1) | (i & 1);
    return batch * (G >> 2) + within;
}

// interleaved edge-weight element: rows j<2O: AF0 AD0 AF1 AD1...; j>=2O: GF0 GD0...
static __device__ __forceinline__ float wbig_val(const float* __restrict__ Wf,
                                                 const float* __restrict__ Wd,
                                                 int j, int c, int O, int C)
{
    if (j < 2 * O) {
        int o = j >> 1;
        return (j & 1) ? Wd[o * 2 * C + c] : Wf[o * 2 * C + c];
    }
    int o = (j - 2 * O) >> 1;
    return (j & 1) ? (Wd[o * 2 * C + C + c] - Wd[o * 2 * C + c])
                   : (Wf[o * 2 * C + C + c] - Wf[o * 2 * C + c]);
}

// fragment-order permute for NT MFMA B operands read straight from global:
// value(r,c) stored at (((c>>5)*RB + (r>>4))*64 + ((c>>3)&3)*16 + (r&15))*8 + (c&7)
// so fragment (rowblock, kstep) loads are base + lane*8 -> coalesced 1KB/wave.
static __device__ __forceinline__ int frag_ix(int r, int c, int RB)
{
    return (((c >> 5) * RB + (r >> 4)) * 64 + ((c >> 3) & 3) * 16 + (r & 15)) * 8 + (c & 7);
}

// ---------------------------------------------------------------------------
// prep+knn mega-kernel: blocks [0, NBP/4) run KNN (4 waves, one query per
// wave); remaining blocks run layer-1 GEMM + all weight builds.
// Wc frag-ordered (RB=12); Wi1 frag-ordered 256x128 (RB=16); Wi2 interleaved
// frag-ordered (RB=32); Wb4 frag-ordered (512x64, RB=32) for edge_gemm4's
// direct-global B loads.
// ---------------------------------------------------------------------------
#define PC0 1572864          // l1: MROWS*64 -> AH/AG
#define PC1 (PC0 + 4096)     // Wb2 (O=32,C=16,Kp=32)
#define PC2 (PC1 + 8192)     // Wb3 (O=64,C=32,Kp=32)
#define PC3 (PC2 + 32768)    // Wb4 frag-ordered (512 x 64)
#define PC4 (PC3 + 49152)    // Wc frag-ordered (192 x 256)
#define PC5 (PC4 + 32768)    // Wi1 frag-ordered (256 x 128)
#define PC6 (PC5 + 65536)    // Wi2 interleaved frag-ordered (512 x 128)
#define KNN_BLOCKS (NBP / 4)       // 2048
#define PREP_BLOCKS (PC6 / 256)    // 6896

__global__ __launch_bounds__(256) void prep_knn_kernel(
    const float* __restrict__ x, int* __restrict__ idx,
    __half* __restrict__ AH, float* __restrict__ AG,
    const float* __restrict__ w1f, const float* __restrict__ w1d,
    const float* __restrict__ w2f, const float* __restrict__ w2d,
    unsigned short* __restrict__ Wb2h, unsigned short* __restrict__ Wb2l,
    const float* __restrict__ w3f, const float* __restrict__ w3d,
    unsigned short* __restrict__ Wb3h, unsigned short* __restrict__ Wb3l,
    const float* __restrict__ w4f, const float* __restrict__ w4d,
    unsigned short* __restrict__ Wb4h, unsigned short* __restrict__ Wb4l,
    const float* __restrict__ wcf, const float* __restrict__ wcd,
    unsigned short* __restrict__ Wch, unsigned short* __restrict__ Wcl,
    const float* __restrict__ wi1f, const float* __restrict__ wi1d,
    unsigned short* __restrict__ Wi1h, unsigned short* __restrict__ Wi1l,
    const float* __restrict__ wi2f, const float* __restrict__ wi2d,
    unsigned short* __restrict__ Wi2h, unsigned short* __restrict__ Wi2l)
{
    __shared__ unsigned ksh[4][64 * 34];
    if (blockIdx.x < KNN_BLOCKS) {
        // ---- KNN: one query per wave, keys in this wave's LDS slice ----
        const int t  = threadIdx.x & 63;
        const int wq = threadIdx.x >> 6;
        const int bn = blockIdx.x * 4 + wq;
        const int b = bn >> 11;
        const int n = bn & (NPTS - 1);
        const float* xb = x + b * 3 * NPTS;
        const float qx = xb[n], qy = xb[NPTS + n], qz = xb[2 * NPTS + n];
        const float sqn = fmaf(qz, qz, fmaf(qy, qy, qx * qx));
        unsigned* ks = &ksh[wq][t * 34];

        unsigned gm[4];
        int ga[4];
#pragma unroll
        for (int g = 0; g < 4; g++) {
            unsigned kk[8];
#pragma unroll
            for (int j = 0; j < 8; j++) {
                const int i = g * 8 + j;
                const int m = (i << 6) + t;
                float mx = xb[m], my = xb[NPTS + m], mz = xb[2 * NPTS + m];
                float sqm = fmaf(mz, mz, fmaf(my, my, mx * mx));
                float dt  = fmaf(qz, mz, fmaf(qy, my, qx * mx));
                float d2  = sqn + sqm - 2.0f * dt;
                unsigned u = __float_as_uint(d2);
                u ^= (u & 0x80000000u) ? 0xFFFFFFFFu : 0x80000000u;  // monotone map
                kk[j] = u;
            }
            *(uint2*)&ks[g * 8 + 0] = make_uint2(kk[0], kk[1]);
            *(uint2*)&ks[g * 8 + 2] = make_uint2(kk[2], kk[3]);
            *(uint2*)&ks[g * 8 + 4] = make_uint2(kk[4], kk[5]);
            *(uint2*)&ks[g * 8 + 6] = make_uint2(kk[6], kk[7]);
            unsigned bg = kk[0];
            int ba = g * 8;
#pragma unroll
            for (int j = 1; j < 8; j++) {
                if (kk[j] < bg) { bg = kk[j]; ba = g * 8 + j; }
            }
            gm[g] = bg; ga[g] = ba;
        }
        unsigned lm = gm[0];
        int il = ga[0];
#pragma unroll
        for (int g = 1; g < 4; g++) if (gm[g] < lm) { lm = gm[g]; il = ga[g]; }

        unsigned long long pk = ((unsigned long long)lm << 32) | (unsigned)((il << 6) | t);
        int res = -1;
        for (int r = 0; r < KNN_K; r++) {
            unsigned long long w = pk;
#pragma unroll
            for (int off = 32; off > 0; off >>= 1) {
                unsigned long long o = shfl_xor_u64(w, off);
                w = (o < w) ? o : w;
            }
            if (t == r) res = (int)(w & 0xFFFFFFFFull);

            if (pk == w) {                    // exactly one owner lane (m unique)
                ks[il] = 0xFFFFFFFFu;
                const int g = il >> 3;
                unsigned bg = ks[g * 8];
                int ba = g * 8;
#pragma unroll
                for (int j = 1; j < 8; j++) {
                    unsigned kv = ks[g * 8 + j];
                    if (kv < bg) { bg = kv; ba = g * 8 + j; }
                }
                gm[g] = bg; ga[g] = ba;
                lm = gm[0]; il = ga[0];
#pragma unroll
                for (int g2 = 1; g2 < 4; g2++) if (gm[g2] < lm) { lm = gm[g2]; il = ga[g2]; }
                pk = ((unsigned long long)lm << 32) | (unsigned)((il << 6) | t);
            }
        }
        if (t < KNN_K) idx[bn * KNN_K + t] = res;
        return;
    }

    // ---- prep: layer-1 + weight builds ----
    const int i = (blockIdx.x - KNN_BLOCKS) * 256 + threadIdx.x;
    if (i < PC0) {
        int o = i & 63;
        int row = i >> 6;
        int v = row % 3;
        int gp = row / 3;
        int b = gp >> 11;
        int n = gp & (NPTS - 1);
        float xv = x[(b * 3 + v) * NPTS + n];
        float wv = wbig_val(w1f, w1d, o, 0, 16, 1);
        float val = xv * wv;
        if (o < 32) AH[(size_t)row * 32 + o] = __float2half(val);
        else        AG[(size_t)row * 32 + o - 32] = val;
    } else if (i < PC6) {
        float v = 0.f;
        unsigned short *ph, *pl;
        int ix;
        if (i < PC1) {            // Wb2: O=32,C=16,Kpad=32
            ix = i - PC0;
            int c = ix & 31, j = ix >> 5;
            if (c < 16) v = wbig_val(w2f, w2d, j, c, 32, 16);
            ph = Wb2h; pl = Wb2l;
        } else if (i < PC2) {     // Wb3: O=64,C=32,Kpad=32
            ix = i - PC1;
            int c = ix & 31, j = ix >> 5;
            v = wbig_val(w3f, w3d, j, c, 64, 32);
            ph = Wb3h; pl = Wb3l;
        } else if (i < PC3) {     // Wb4 frag-ordered: 512 rows x 64 k (RB=32)
            ix = i - PC2;
            int c = ix & 63, r = ix >> 6;
            v = wbig_val(w4f, w4d, r, c, 128, 64);
            ph = Wb4h; pl = Wb4l;
            ix = frag_ix(r, c, 32);
        } else if (i < PC4) {     // Wc frag-ordered: 192 rows x 256 k (RB=12)
            ix = i - PC3;
            int c = ix & 255, r = ix >> 8;
            if (c < 240) {
                if (r < 128) v = wcf[r * 240 + c];
                else if (r < 129) v = wcd[(r - 128) * 240 + c];
            }
            ph = Wch; pl = Wcl;
            ix = frag_ix(r, c, 12);
        } else if (i < PC5) {     // Wi1 frag-ordered: 256 rows x 128 k (RB=16)
            ix = i - PC4;
            int c = ix & 127, r = ix >> 7;
            if (r < 128) v = wi1f[r * 256 + c];
            else v = wi1d[(r - 128) * 256 + c];
            ph = Wi1h; pl = Wi1l;
            ix = frag_ix(r, c, 16);
        } else {                  // Wi2 interleaved rows (2o=f,2o+1=d), frag-ordered (RB=32)
            ix = i - PC5;
            int c = ix & 127, r = ix >> 7;
            int o = r >> 1;
            v = (r & 1) ? wi2d[o * 128 + c] : wi2f[o * 128 + c];
            ph = Wi2h; pl = Wi2l;
            ix = frag_ix(r, c, 32);
        }
        unsigned short h, l;
        split_bf16(v, h, l);
        ph[ix] = h; pl[ix] = l;
    }
}

// ---------------------------------------------------------------------------
// Fused edge + gemm (layers 2 and 3). Block = 16 points (48 rows), 4 waves.
// ---------------------------------------------------------------------------
template <int OIN, int NF>
__global__ __launch_bounds__(256, 3) void edge_gemm_kernel(
    const __half* __restrict__ AHin, const float* __restrict__ AGin,
    const int* __restrict__ idx,
    unsigned short* __restrict__ X240h, unsigned short* __restrict__ X240l, int ooff,
    const unsigned short* __restrict__ Wh, const unsigned short* __restrict__ Wl,
    __half* __restrict__ OUTA, float* __restrict__ OUTG)
{
    constexpr int PTS = 16;
    constexpr int NC = NF * 64;        // gemm output cols (2*twoO_out)
    constexpr int twoO = NC / 2;
    constexpr int LDW = 40;            // W LDS row stride (u16)
    constexpr int CPT = OIN / 16;      // channels per thread: 1 (O=16) or 2 (O=32)
    constexpr int twoOin = 2 * OIN;

    __shared__ unsigned short Xsh[48][32];
    __shared__ unsigned short Xsl[48][32];
    __shared__ unsigned short wbh[NC][LDW];
    __shared__ unsigned short wbl[NC][LDW];
    __shared__ int sIdx[PTS][KNN_K];

    const int lb = xcd_swizzle(blockIdx.x, gridDim.x);
    const int tid = threadIdx.x;

    // stage W + idx (W has no dependence on edge outputs)
    for (int rr = tid; rr < NC; rr += 256) {
#pragma unroll
        for (int scc = 0; scc < 4; scc++) {
            *(uint4*)&wbh[rr][scc * 8] = *(const uint4*)(Wh + (size_t)rr * 32 + scc * 8);
            *(uint4*)&wbl[rr][scc * 8] = *(const uint4*)(Wl + (size_t)rr * 32 + scc * 8);
        }
    }
    for (int j = tid; j < PTS * KNN_K; j += 256)
        sIdx[j >> 4][j & 15] = idx[(lb * PTS + (j >> 4)) * KNN_K + (j & 15)];
    __syncthreads();

    // ---- edge phase: 16 threads per point, CPT channels per thread ----
    const int op = tid & 15;
    const int pt = tid >> 4;
    const int gp = lb * PTS + pt;
    const int b = gp >> 11;
    const int rown = gp * 3;
    const int bbase = (b << 11) * 3;

    float cg[3][2 * CPT];
#pragma unroll
    for (int v = 0; v < 3; v++) {
        if constexpr (CPT == 2) {
            float4 c4 = *(const float4*)&AGin[(size_t)(rown + v) * twoOin + 4 * op];
            cg[v][0] = c4.x; cg[v][1] = c4.y; cg[v][2] = c4.z; cg[v][3] = c4.w;
        } else {
            float2 c2 = *(const float2*)&AGin[(size_t)(rown + v) * twoOin + 2 * op];
            cg[v][0] = c2.x; cg[v][1] = c2.y;
        }
    }
    float am[CPT][3];
#pragma unroll
    for (int c0 = 0; c0 < CPT; c0++) { am[c0][0] = 0.f; am[c0][1] = 0.f; am[c0][2] = 0.f; }

#pragma unroll 2
    for (int k = 0; k < KNN_K; k++) {
        const int m = sIdx[pt][k];
        const __half* base = AHin + (size_t)(bbase + m * 3) * twoOin + 2 * CPT * op;
        float e[3][2 * CPT];
#pragma unroll
        for (int v = 0; v < 3; v++) {
            if constexpr (CPT == 2) {
                uint2 u = *(const uint2*)(base + (size_t)v * twoOin);
                float2 x0 = __half22float2(*(__half2*)&u.x);
                float2 x1 = __half22float2(*(__half2*)&u.y);
                e[v][0] = x0.x; e[v][1] = x0.y; e[v][2] = x1.x; e[v][3] = x1.y;
            } else {
                unsigned u = *(const unsigned*)(base + (size_t)v * twoOin);
                float2 x0 = __half22float2(*(__half2*)&u);
                e[v][0] = x0.x; e[v][1] = x0.y;
            }
        }
#pragma unroll
        for (int c0 = 0; c0 < CPT; c0++) {
            float p0 = e[0][2 * c0] + cg[0][2 * c0], d0 = e[0][2 * c0 + 1] + cg[0][2 * c0 + 1];
            float p1 = e[1][2 * c0] + cg[1][2 * c0], d1 = e[1][2 * c0 + 1] + cg[1][2 * c0 + 1];
            float p2 = e[2][2 * c0] + cg[2][2 * c0], d2 = e[2][2 * c0 + 1] + cg[2][2 * c0 + 1];
            float dot = fmaf(p2, d2, fmaf(p1, d1, p0 * d0));
            float dsq = fmaf(d2, d2, fmaf(d1, d1, d0 * d0));
            float s = lna_scale(dot, dsq);
            am[c0][0] += fmaf(-s, d0, p0);
            am[c0][1] += fmaf(-s, d1, p1);
            am[c0][2] += fmaf(-s, d2, p2);
        }
    }

    // mean, write-through to X240, stage split-bf16 A-tile in LDS
#pragma unroll
    for (int v = 0; v < 3; v++) {
#pragma unroll
        for (int c0 = 0; c0 < CPT; c0++) {
            const int ch = CPT * op + c0;
            unsigned short h, l;
            split_bf16(am[c0][v] * 0.0625f, h, l);
            Xsh[pt * 3 + v][ch] = h;
            Xsl[pt * 3 + v][ch] = l;
            const size_t ob = (size_t)(rown + v) * 256 + ooff + ch;
            X240h[ob] = h; X240l[ob] = l;
        }
        if constexpr (CPT == 1) {      // zero-pad k = 16..32
            Xsh[pt * 3 + v][16 + op] = 0;
            Xsl[pt * 3 + v][16 + op] = 0;
        }
    }
    __syncthreads();

    // ---- gemm phase: one K-step (Kpad=32), waves split N ----
    const int lane = tid & 63;
    const int wv = tid >> 6;
    const int mr = lane & 15;
    const int q  = lane >> 4;

    f32x4 acc[3][NF];
#pragma unroll
    for (int a = 0; a < 3; a++)
#pragma unroll
        for (int c = 0; c < NF; c++) acc[a][c] = (f32x4){0.f, 0.f, 0.f, 0.f};

    bf16x8 ah[3], al[3], bh[NF], bl[NF];
#pragma unroll
    for (int mf = 0; mf < 3; mf++) {
        ah[mf] = *(const bf16x8*)&Xsh[mf * 16 + mr][q * 8];
        al[mf] = *(const bf16x8*)&Xsl[mf * 16 + mr][q * 8];
    }
#pragma unroll
    for (int nf = 0; nf < NF; nf++) {
        const int wr = wv * 16 * NF + nf * 16 + mr;
        bh[nf] = *(const bf16x8*)&wbh[wr][q * 8];
        bl[nf] = *(const bf16x8*)&wbl[wr][q * 8];
    }
#pragma unroll
    for (int mf = 0; mf < 3; mf++)
#pragma unroll
        for (int nf = 0; nf < NF; nf++) {
            acc[mf][nf] = __builtin_amdgcn_mfma_f32_16x16x32_bf16(ah[mf], bh[nf], acc[mf][nf], 0, 0, 0);
            acc[mf][nf] = __builtin_amdgcn_mfma_f32_16x16x32_bf16(ah[mf], bl[nf], acc[mf][nf], 0, 0, 0);
            acc[mf][nf] = __builtin_amdgcn_mfma_f32_16x16x32_bf16(al[mf], bh[nf], acc[mf][nf], 0, 0, 0);
        }

    // epilogue: col split AH (fp16) / AG (fp32) is wave-uniform
    const int rbase = lb * 48;
#pragma unroll
    for (int nf = 0; nf < NF; nf++) {
        const int col = wv * 16 * NF + nf * 16 + mr;
#pragma unroll
        for (int mf = 0; mf < 3; mf++)
#pragma unroll
            for (int i = 0; i < 4; i++) {
                const int row = rbase + mf * 16 + q * 4 + i;
                const float val = acc[mf][nf][i];
                if (col < twoO) OUTA[(size_t)row * twoO + col] = __float2half(val);
                else            OUTG[(size_t)row * twoO + col - twoO] = val;
            }
    }
}

// ---------------------------------------------------------------------------
// Fused layer-3 edge (O=64) + layer-4 GEMM. Block = 16 points (48 rows).
// Edge phase gathers x3 -> split-bf16 LDS + write-through to X240 (cols
// 48..111, needed by edge_wc). GEMM K=64: A from LDS, Wb4 B-frags direct from
// frag-ordered global (no W staging, no K-loop barriers).
// Epilogue writes AH2 (cols<256 fp16) / AG2 (fp32) at ld 256.
// ---------------------------------------------------------------------------
__global__ __launch_bounds__(256, 2) void edge_gemm4_kernel(
    const __half* __restrict__ AHin, const float* __restrict__ AGin,   // ld 128
    const int* __restrict__ idx,
    unsigned short* __restrict__ X240h, unsigned short* __restrict__ X240l,
    const unsigned short* __restrict__ Wh, const unsigned short* __restrict__ Wl, // Wb4 frag RB=32
    __half* __restrict__ OUTA, float* __restrict__ OUTG)               // ld 256
{
    __shared__ unsigned short Xsh[48][72];
    __shared__ unsigned short Xsl[48][72];
    __shared__ int sIdx[16][KNN_K];

    const int lb = xcd_swizzle(blockIdx.x, gridDim.x);
    const int tid = threadIdx.x;

    for (int j = tid; j < 16 * KNN_K; j += 256)
        sIdx[j >> 4][j & 15] = idx[(lb * 16 + (j >> 4)) * KNN_K + (j & 15)];
    __syncthreads();

    // ---- edge phase (OIN=64): 16 thr/pt, 4 channels/thr ----
    {
        const int op = tid & 15;
        const int pt = tid >> 4;
        const int gp = lb * 16 + pt;
        const int b = gp >> 11;
        const int rown = gp * 3;
        const int bbase = (b << 11) * 3;

        float cg[3][8];
#pragma unroll
        for (int v = 0; v < 3; v++) {
            const float* ag = &AGin[(size_t)(rown + v) * 128 + 8 * op];
            float4 c4a = *(const float4*)ag;
            float4 c4b = *(const float4*)(ag + 4);
            cg[v][0] = c4a.x; cg[v][1] = c4a.y; cg[v][2] = c4a.z; cg[v][3] = c4a.w;
            cg[v][4] = c4b.x; cg[v][5] = c4b.y; cg[v][6] = c4b.z; cg[v][7] = c4b.w;
        }
        float am[4][3];
#pragma unroll
        for (int c0 = 0; c0 < 4; c0++) { am[c0][0] = 0.f; am[c0][1] = 0.f; am[c0][2] = 0.f; }

        for (int k = 0; k < KNN_K; k++) {
            const int m = sIdx[pt][k];
            const __half* base = AHin + (size_t)(bbase + m * 3) * 128 + 8 * op;
            unsigned uw[3][4];
#pragma unroll
            for (int v = 0; v < 3; v++) {
                uint4 a = *(const uint4*)(base + (size_t)v * 128);
                uw[v][0] = a.x; uw[v][1] = a.y; uw[v][2] = a.z; uw[v][3] = a.w;
            }
#pragma unroll
            for (int c0 = 0; c0 < 4; c0++) {
                float2 e0 = __half22float2(*(__half2*)&uw[0][c0]);
                float2 e1 = __half22float2(*(__half2*)&uw[1][c0]);
                float2 e2 = __half22float2(*(__half2*)&uw[2][c0]);
                float p0 = e0.x + cg[0][2 * c0], d0 = e0.y + cg[0][2 * c0 + 1];
                float p1 = e1.x + cg[1][2 * c0], d1 = e1.y + cg[1][2 * c0 + 1];
                float p2 = e2.x + cg[2][2 * c0], d2 = e2.y + cg[2][2 * c0 + 1];
                float dot = fmaf(p2, d2, fmaf(p1, d1, p0 * d0));
                float dsq = fmaf(d2, d2, fmaf(d1, d1, d0 * d0));
                float s = lna_scale(dot, dsq);
                am[c0][0] += fmaf(-s, d0, p0);
                am[c0][1] += fmaf(-s, d1, p1);
                am[c0][2] += fmaf(-s, d2, p2);
            }
        }
#pragma unroll
        for (int v = 0; v < 3; v++)
#pragma unroll
            for (int c0 = 0; c0 < 4; c0++) {
                const int ch = 4 * op + c0;
                unsigned short h, l;
                split_bf16(am[c0][v] * 0.0625f, h, l);
                Xsh[pt * 3 + v][ch] = h;
                Xsl[pt * 3 + v][ch] = l;
                const size_t ob = (size_t)(rown + v) * 256 + 48 + ch;
                X240h[ob] = h; X240l[ob] = l;
            }
    }
    __syncthreads();

    // ---- gemm phase: K=64 (2 k-steps), A from LDS, B frag-ordered global ----
    const int lane = tid & 63;
    const int wv = tid >> 6;
    const int mr = lane & 15;
    const int q  = lane >> 4;

    f32x4 acc[3][8];
#pragma unroll
    for (int a = 0; a < 3; a++)
#pragma unroll
        for (int c = 0; c < 8; c++) acc[a][c] = (f32x4){0.f, 0.f, 0.f, 0.f};

    for (int ks = 0; ks < 2; ks++) {
        bf16x8 ah[3], al[3];
#pragma unroll
        for (int mf = 0; mf < 3; mf++) {
            ah[mf] = *(const bf16x8*)&Xsh[mf * 16 + mr][ks * 32 + q * 8];
            al[mf] = *(const bf16x8*)&Xsl[mf * 16 + mr][ks * 32 + q * 8];
        }
#pragma unroll
        for (int nf = 0; nf < 8; nf++) {
            const size_t wi = (size_t)((ks * 32 + wv * 8 + nf) * 64 + lane) * 8;
            const bf16x8 bh = *(const bf16x8*)(Wh + wi);
            const bf16x8 bl = *(const bf16x8*)(Wl + wi);
#pragma unroll
            for (int mf = 0; mf < 3; mf++) {
                acc[mf][nf] = __builtin_amdgcn_mfma_f32_16x16x32_bf16(ah[mf], bh, acc[mf][nf], 0, 0, 0);
                acc[mf][nf] = __builtin_amdgcn_mfma_f32_16x16x32_bf16(ah[mf], bl, acc[mf][nf], 0, 0, 0);
                acc[mf][nf] = __builtin_amdgcn_mfma_f32_16x16x32_bf16(al[mf], bh, acc[mf][nf], 0, 0, 0);
            }
        }
    }

    // epilogue: col = wv*128 + nf*16 + mr (wave-uniform AH/AG split)
    const int rbase = lb * 48;
#pragma unroll
    for (int nf = 0; nf < 8; nf++) {
        const int col = wv * 128 + nf * 16 + mr;
#pragma unroll
        for (int mf = 0; mf < 3; mf++)
#pragma unroll
            for (int i = 0; i < 4; i++) {
                const int row = rbase + mf * 16 + q * 4 + i;
                const float val = acc[mf][nf][i];
                if (col < 256) OUTA[(size_t)row * 256 + col] = __float2half(val);
                else           OUTG[(size_t)row * 256 + col - 256] = val;
            }
    }
}

// ---------------------------------------------------------------------------
// Fused layer-4 edge (O=128) + wc GEMM + lna. Block = 16 points.
// Wc B-frags read via frag-order (coalesced); tb unions the x4 LDS region.
// ---------------------------------------------------------------------------
#define EW_LDX 136   // x4 u16 stride
#define EW_LDT 133   // tb fp32 stride
__global__ __launch_bounds__(256, 4) void edge_wc_kernel(
    const __half* __restrict__ AHin, const float* __restrict__ AGin,   // ld 256
    const int* __restrict__ idx,
    const unsigned short* __restrict__ Xh, const unsigned short* __restrict__ Xl, // X240 ld 256 (cols 0..111)
    const unsigned short* __restrict__ Wh, const unsigned short* __restrict__ Wl, // Wc frag-ordered 192x256
    unsigned short* __restrict__ oh, unsigned short* __restrict__ ol,  // xc2 ld 128
    float* __restrict__ part2)
{
    // union: x4h(13056) + x4l(13056) = 26112B; tb needs 48*133*4 = 25536B
    __shared__ __align__(16) char smem[48 * EW_LDX * 2 * 2];
    unsigned short (*x4h)[EW_LDX] = (unsigned short (*)[EW_LDX])smem;
    unsigned short (*x4l)[EW_LDX] = (unsigned short (*)[EW_LDX])(smem + 48 * EW_LDX * 2);
    float* tb = (float*)smem;
    __shared__ int sIdx[16][KNN_K];

    const int lb = xcd_swizzle(blockIdx.x, gridDim.x);
    const int tid = threadIdx.x;

    for (int j = tid; j < 16 * KNN_K; j += 256)
        sIdx[j >> 4][j & 15] = idx[(lb * 16 + (j >> 4)) * KNN_K + (j & 15)];
    __syncthreads();

    // ---- edge phase: 16 thr/pt, 8 channels/thr ----
    {
        const int op = tid & 15;
        const int pt = tid >> 4;
        const int gp = lb * 16 + pt;
        const int b = gp >> 11;
        const int rown = gp * 3;
        const int bbase = (b << 11) * 3;

        float cg[3][16];
#pragma unroll
        for (int v = 0; v < 3; v++) {
            const float* ag = &AGin[(size_t)(rown + v) * 256 + 16 * op];
#pragma unroll
            for (int t = 0; t < 4; t++) {
                float4 c4 = *(const float4*)(ag + 4 * t);
                cg[v][4 * t + 0] = c4.x; cg[v][4 * t + 1] = c4.y;
                cg[v][4 * t + 2] = c4.z; cg[v][4 * t + 3] = c4.w;
            }
        }
        float am[8][3];
#pragma unroll
        for (int c0 = 0; c0 < 8; c0++) { am[c0][0] = 0.f; am[c0][1] = 0.f; am[c0][2] = 0.f; }

        for (int k = 0; k < KNN_K; k++) {
            const int m = sIdx[pt][k];
            const __half* base = AHin + (size_t)(bbase + m * 3) * 256 + 16 * op;
            unsigned uw[3][8];
#pragma unroll
            for (int v = 0; v < 3; v++) {
                uint4 a  = *(const uint4*)(base + (size_t)v * 256);
                uint4 bq = *(const uint4*)(base + (size_t)v * 256 + 8);
                uw[v][0] = a.x;  uw[v][1] = a.y;  uw[v][2] = a.z;  uw[v][3] = a.w;
                uw[v][4] = bq.x; uw[v][5] = bq.y; uw[v][6] = bq.z; uw[v][7] = bq.w;
            }
#pragma unroll
            for (int c0 = 0; c0 < 8; c0++) {
                float2 e0 = __half22float2(*(__half2*)&uw[0][c0]);
                float2 e1 = __half22float2(*(__half2*)&uw[1][c0]);
                float2 e2 = __half22float2(*(__half2*)&uw[2][c0]);
                float p0 = e0.x + cg[0][2 * c0], d0 = e0.y + cg[0][2 * c0 + 1];
                float p1 = e1.x + cg[1][2 * c0], d1 = e1.y + cg[1][2 * c0 + 1];
                float p2 = e2.x + cg[2][2 * c0], d2 = e2.y + cg[2][2 * c0 + 1];
                float dot = fmaf(p2, d2, fmaf(p1, d1, p0 * d0));
                float dsq = fmaf(d2, d2, fmaf(d1, d1, d0 * d0));
                float s = lna_scale(dot, dsq);
                am[c0][0] += fmaf(-s, d0, p0);
                am[c0][1] += fmaf(-s, d1, p1);
                am[c0][2] += fmaf(-s, d2, p2);
            }
        }
#pragma unroll
        for (int v = 0; v < 3; v++)
#pragma unroll
            for (int c0 = 0; c0 < 8; c0++) {
                unsigned short h, l;
                split_bf16(am[c0][v] * 0.0625f, h, l);
                x4h[pt * 3 + v][8 * op + c0] = h;
                x4l[pt * 3 + v][8 * op + c0] = l;
            }
    }
    __syncthreads();

    // ---- wc GEMM: K=256 pad, A source select, B frag-ordered from global ----
    const int lane = tid & 63;
    const int wv = tid >> 6;
    const int mr = lane & 15;
    const int q  = lane >> 4;
    const int rbase = lb * 48;

    f32x4 acc[3][3];
#pragma unroll
    for (int a = 0; a < 3; a++)
#pragma unroll
        for (int c = 0; c < 3; c++) acc[a][c] = (f32x4){0.f, 0.f, 0.f, 0.f};

    for (int k0 = 0; k0 < 256; k0 += 32) {
        const int kb = k0 + q * 8;
        bf16x8 ah[3], al[3], bh[3], bl[3];
#pragma unroll
        for (int mf = 0; mf < 3; mf++) {
            const int row = mf * 16 + mr;
            if (kb >= 112) {
                if (kb >= 240) {
                    ah[mf] = (bf16x8){0, 0, 0, 0, 0, 0, 0, 0};
                    al[mf] = (bf16x8){0, 0, 0, 0, 0, 0, 0, 0};
                } else {
                    ah[mf] = *(const bf16x8*)&x4h[row][kb - 112];
                    al[mf] = *(const bf16x8*)&x4l[row][kb - 112];
                }
            } else {
                const size_t xr = (size_t)(rbase + row) * 256 + kb;
                ah[mf] = *(const bf16x8*)(Xh + xr);
                al[mf] = *(const bf16x8*)(Xl + xr);
            }
        }
#pragma unroll
        for (int nf = 0; nf < 3; nf++) {
            const size_t wri = (size_t)((((k0 >> 5) * 12) + wv * 3 + nf) * 64 + lane) * 8;
            bh[nf] = *(const bf16x8*)(Wh + wri);
            bl[nf] = *(const bf16x8*)(Wl + wri);
        }
#pragma unroll
        for (int mf = 0; mf < 3; mf++)
#pragma unroll
            for (int nf = 0; nf < 3; nf++) {
                acc[mf][nf] = __builtin_amdgcn_mfma_f32_16x16x32_bf16(ah[mf], bh[nf], acc[mf][nf], 0, 0, 0);
                acc[mf][nf] = __builtin_amdgcn_mfma_f32_16x16x32_bf16(ah[mf], bl[nf], acc[mf][nf], 0, 0, 0);
                acc[mf][nf] = __builtin_amdgcn_mfma_f32_16x16x32_bf16(al[mf], bh[nf], acc[mf][nf], 0, 0, 0);
            }
    }
    __syncthreads();   // x4 dead; tb overlays it

    // stage cols 0..128 (p cols + shared d col)
#pragma unroll
    for (int mf = 0; mf < 3; mf++)
#pragma unroll
        for (int nf = 0; nf < 3; nf++) {
            const int col = wv * 48 + nf * 16 + mr;
            if (col <= 128) {
#pragma unroll
                for (int i = 0; i < 4; i++)
                    tb[(mf * 16 + q * 4 + i) * EW_LDT + col] = acc[mf][nf][i];
            }
        }
    __syncthreads();

    const int bp0 = lb * 16;
    float vacc[3] = {0.f, 0.f, 0.f};
#pragma unroll
    for (int it = 0; it < 8; it++) {
        const int item = it * 256 + tid;   // 2048 = 16 pts x 128 o
        const int o = item & 127;
        const int pt = item >> 7;
        float p[3], d[3];
#pragma unroll
        for (int v = 0; v < 3; v++) {
            const int r = pt * 3 + v;
            p[v] = tb[r * EW_LDT + o];
            d[v] = tb[r * EW_LDT + 128];
        }
        float dot = fmaf(p[2], d[2], fmaf(p[1], d[1], p[0] * d[0]));
        float dsq = fmaf(d[2], d[2], fmaf(d[1], d[1], d[0] * d[0]));
        float s = lna_scale(dot, dsq);
#pragma unroll
        for (int v = 0; v < 3; v++) {
            float val = fmaf(-s, d[v], p[v]);
            vacc[v] += val;
            unsigned short h, l;
            split_bf16(val, h, l);
            const size_t ob = ((size_t)(bp0 + pt) * 3 + v) * 128 + o;
            oh[ob] = h; ol[ob] = l;
        }
    }

    __syncthreads();
    tb[tid] = vacc[0]; tb[256 + tid] = vacc[1]; tb[512 + tid] = vacc[2];
    __syncthreads();
    if (tid < 128) {
#pragma unroll
        for (int v = 0; v < 3; v++)
            part2[(size_t)lb * 384 + v * 128 + tid] =
                tb[v * 256 + tid] + tb[v * 256 + tid + 128];
    }
}

// ---------------------------------------------------------------------------
// xm reduce + ym: part2[512][3][128] -> xm (bf16-pair, 12x128) AND
// ym[12][256] = xm @ Wi1stack[:,128:256]^T (constant K>=128 part of wi1).
// ---------------------------------------------------------------------------
__global__ __launch_bounds__(128) void xm_reduce_ym_kernel(
    const float* __restrict__ part2,
    unsigned short* __restrict__ xmh, unsigned short* __restrict__ xml,
    const float* __restrict__ wi1f, const float* __restrict__ wi1d,
    float* __restrict__ ym)
{
    __shared__ float xs[128];
    const int bv = blockIdx.x;       // 12 = b*3+v
    const int b = bv / 3;
    const int v = bv % 3;
    const int o = threadIdx.x;       // 128
    float acc = 0.f;
    for (int i = 0; i < 128; i++)
        acc += part2[(size_t)(b * 128 + i) * 384 + v * 128 + o];
    const float m = acc * (1.f / 2048.f);
    unsigned short h, l;
    split_bf16(m, h, l);
    xmh[bv * 128 + o] = h;
    xml[bv * 128 + o] = l;
    xs[o] = m;
    __syncthreads();
#pragma unroll
    for (int half = 0; half < 2; half++) {
        const int oo = half * 128 + o;
        const float* wrow = (oo < 128) ? (wi1f + (size_t)oo * 256 + 128)
                                       : (wi1d + (size_t)(oo - 128) * 256 + 128);
        float s = 0.f;
        for (int c = 0; c < 128; c++) s = fmaf(wrow[c], xs[c], s);
        ym[(size_t)bv * 256 + oo] = s;
    }
}

// ---------------------------------------------------------------------------
// Fused wi1 + wi2 + inv. Phase-1 B loads direct from frag-ordered global Wi1
// (no staging, no K-loop barriers); tb epilogue / y1 LDS / phase 2 as R16.
// ---------------------------------------------------------------------------
#define QI_LDY  136    // y1 u16 stride
#define QI_LDT  257    // phase-1 tb fp32 stride
#define QI_LDT2 67     // phase-2 per-wave tile fp32 stride
__global__ __launch_bounds__(256, 2) void gemm_ii_kernel(
    const unsigned short* __restrict__ xch, const unsigned short* __restrict__ xcl, // ld 128
    const unsigned short* __restrict__ W1h, const unsigned short* __restrict__ W1l, // Wi1 frag 256x128
    const unsigned short* __restrict__ W2h, const unsigned short* __restrict__ W2l, // Wi2 frag 512x128 (ilv)
    const unsigned short* __restrict__ xmh, const unsigned short* __restrict__ xml,
    const float* __restrict__ ym,
    float* __restrict__ out)
{
    __shared__ __align__(16) char regA[51456];   // union: tb(49344) / wt(51456)
    __shared__ __align__(16) unsigned short y1h[48][QI_LDY];
    __shared__ __align__(16) unsigned short y1l[48][QI_LDY];
    float* tb = (float*)regA;

    const int tid = threadIdx.x;
    const int lane = tid & 63;
    const int wv = tid >> 6;
    const int mr = lane & 15;
    const int q  = lane >> 4;
    const int lb = blockIdx.x;
    const int bm = lb * 48;
    const int bb = (lb * 16) >> 11;   // batch (uniform: 16 | 2048)

    // ---- phase 1: wi1 GEMM (N=256, K=128), B direct frag-ordered global ----
    f32x4 acc[3][4];
#pragma unroll
    for (int a = 0; a < 3; a++)
#pragma unroll
        for (int c = 0; c < 4; c++) acc[a][c] = (f32x4){0.f, 0.f, 0.f, 0.f};

    for (int k0 = 0; k0 < 128; k0 += 32) {
        bf16x8 ah[3], al[3];
#pragma unroll
        for (int mf = 0; mf < 3; mf++) {
            const size_t xr = (size_t)(bm + mf * 16 + mr) * 128 + k0 + q * 8;
            ah[mf] = *(const bf16x8*)(xch + xr);
            al[mf] = *(const bf16x8*)(xcl + xr);
        }
        const int ks = k0 >> 5;
#pragma unroll
        for (int nf = 0; nf < 4; nf++) {
            const size_t wi = (size_t)((ks * 16 + wv * 4 + nf) * 64 + lane) * 8;
            const bf16x8 bh = *(const bf16x8*)(W1h + wi);
            const bf16x8 bl = *(const bf16x8*)(W1l + wi);
#pragma unroll
            for (int mf = 0; mf < 3; mf++) {
                acc[mf][nf] = __builtin_amdgcn_mfma_f32_16x16x32_bf16(ah[mf], bh, acc[mf][nf], 0, 0, 0);
                acc[mf][nf] = __builtin_amdgcn_mfma_f32_16x16x32_bf16(ah[mf], bl, acc[mf][nf], 0, 0, 0);
                acc[mf][nf] = __builtin_amdgcn_mfma_f32_16x16x32_bf16(al[mf], bh, acc[mf][nf], 0, 0, 0);
            }
        }
    }

    // stage PD tile: row = mf*16 + q*4 + i, col = wv*64 + nf*16 + mr
#pragma unroll
    for (int mf = 0; mf < 3; mf++)
#pragma unroll
        for (int nf = 0; nf < 4; nf++)
#pragma unroll
            for (int i = 0; i < 4; i++)
                tb[(size_t)(mf * 16 + q * 4 + i) * QI_LDT + wv * 64 + nf * 16 + mr] = acc[mf][nf][i];
    __syncthreads();

    // epilogue 1: lna(+ym) -> y1 LDS
    {
        const int oo = tid & 127;
        float ymp[3], ymd[3];
#pragma unroll
        for (int v = 0; v < 3; v++) {
            ymp[v] = ym[(size_t)(bb * 3 + v) * 256 + oo];
            ymd[v] = ym[(size_t)(bb * 3 + v) * 256 + 128 + oo];
        }
#pragma unroll
        for (int it = 0; it < 8; it++) {
            const int item = it * 256 + tid;   // 2048 = 16 pts x 128 o  (o == oo)
            const int o = item & 127;
            const int pt = item >> 7;
            float p[3], d[3];
#pragma unroll
            for (int v = 0; v < 3; v++) {
                const int r = pt * 3 + v;
                p[v] = tb[(size_t)r * QI_LDT + o] + ymp[v];
                d[v] = tb[(size_t)r * QI_LDT + 128 + o] + ymd[v];
            }
            float dot = fmaf(p[2], d[2], fmaf(p[1], d[1], p[0] * d[0]));
            float dsq = fmaf(d[2], d[2], fmaf(d[1], d[1], d[0] * d[0]));
            float s = lna_scale(dot, dsq);
#pragma unroll
            for (int v = 0; v < 3; v++) {
                unsigned short h, l;
                split_bf16(fmaf(-s, d[v], p[v]), h, l);
                y1h[pt * 3 + v][o] = h;
                y1l[pt * 3 + v][o] = l;
            }
        }
    }
    __syncthreads();

    // ---- phase 2: wi2 GEMM (N=512, K=128), A from y1 LDS, B frag-ordered global ----
    f32x4 acc2[3][8];
#pragma unroll
    for (int a = 0; a < 3; a++)
#pragma unroll
        for (int c = 0; c < 8; c++) acc2[a][c] = (f32x4){0.f, 0.f, 0.f, 0.f};

    for (int k0 = 0; k0 < 128; k0 += 32) {
        bf16x8 ah[3], al[3];
#pragma unroll
        for (int mf = 0; mf < 3; mf++) {
            ah[mf] = *(const bf16x8*)&y1h[mf * 16 + mr][k0 + q * 8];
            al[mf] = *(const bf16x8*)&y1l[mf * 16 + mr][k0 + q * 8];
        }
#pragma unroll
        for (int nf = 0; nf < 8; nf++) {
            const size_t wi = (size_t)((((k0 >> 5) * 32) + wv * 8 + nf) * 64 + lane) * 8;
            const bf16x8 bh = *(const bf16x8*)(W2h + wi);
            const bf16x8 bl = *(const bf16x8*)(W2l + wi);
#pragma unroll
            for (int mf = 0; mf < 3; mf++) {
                acc2[mf][nf] = __builtin_amdgcn_mfma_f32_16x16x32_bf16(ah[mf], bh, acc2[mf][nf], 0, 0, 0);
                acc2[mf][nf] = __builtin_amdgcn_mfma_f32_16x16x32_bf16(ah[mf], bl, acc2[mf][nf], 0, 0, 0);
                acc2[mf][nf] = __builtin_amdgcn_mfma_f32_16x16x32_bf16(al[mf], bh, acc2[mf][nf], 0, 0, 0);
            }
        }
    }

    // epilogue 2: per-wave 2-half tile staging -> lna + inv -> out
    float* wt = tb + wv * (48 * QI_LDT2);
#pragma unroll
    for (int hf = 0; hf < 2; hf++) {
        __syncthreads();   // regA reuse fence (uniform)
#pragma unroll
        for (int mf = 0; mf < 3; mf++)
#pragma unroll
            for (int nf2 = 0; nf2 < 4; nf2++)
#pragma unroll
                for (int i = 0; i < 4; i++)
                    wt[(mf * 16 + q * 4 + i) * QI_LDT2 + nf2 * 16 + mr] = acc2[mf][hf * 4 + nf2][i];
#pragma unroll
        for (int j = 0; j < 8; j++) {
            const int item = j * 64 + lane;   // 512 = 16 pts x 32 og-local
            const int ol = item & 31;
            const int pt = item >> 5;
            const int og = wv * 64 + hf * 32 + ol;
            const int gp = lb * 16 + pt;
            float p[3], d[3], xc[3];
#pragma unroll
            for (int v = 0; v < 3; v++) {
                p[v] = wt[(3 * pt + v) * QI_LDT2 + 2 * ol];
                d[v] = wt[(3 * pt + v) * QI_LDT2 + 2 * ol + 1];
                if (og < 128) {
                    const size_t ix = (size_t)(gp * 3 + v) * 128 + og;
                    xc[v] = bf2(xch[ix], xcl[ix]);
                } else {
                    const size_t ix = (size_t)(bb * 3 + v) * 128 + og - 128;
                    xc[v] = bf2(xmh[ix], xml[ix]);
                }
            }
            float dot = fmaf(p[2], d[2], fmaf(p[1], d[1], p[0] * d[0]));
            float dsq = fmaf(d[2], d[2], fmaf(d[1], d[1], d[0] * d[0]));
            float s = lna_scale(dot, dsq);
            float inv = 0.f;
#pragma unroll
            for (int v = 0; v < 3; v++)
                inv = fmaf(xc[v], fmaf(-s, d[v], p[v]), inv);
            out[((size_t)bb * 256 + og) * NPTS + (gp & (NPTS - 1))] = inv;
        }
    }
}

// ---------------------------------------------------------------------------
// launch
// ---------------------------------------------------------------------------
extern "C" void kernel_launch(void* const* d_in, const int* in_sizes, int n_in,
                              void* d_out, int out_size, void* d_ws, size_t ws_size,
                              hipStream_t stream)
{
    const float* x    = (const float*)d_in[0];
    const float* w1f  = (const float*)d_in[1];
    const float* w1d  = (const float*)d_in[2];
    const float* w2f  = (const float*)d_in[3];
    const float* w2d  = (const float*)d_in[4];
    const float* w3f  = (const float*)d_in[5];
    const float* w3d  = (const float*)d_in[6];
    const float* w4f  = (const float*)d_in[7];
    const float* w4d  = (const float*)d_in[8];
    const float* wcf  = (const float*)d_in[9];
    const float* wcd  = (const float*)d_in[10];
    const float* wi1f = (const float*)d_in[11];
    const float* wi1d = (const float*)d_in[12];
    const float* wi2f = (const float*)d_in[13];
    const float* wi2d = (const float*)d_in[14];
    float* out = (float*)d_out;

    float* F = (float*)d_ws;
    size_t off = 0;
    float* AG = F + off;                          off += (size_t)MROWS * 512;  // AG1 = AG, AG2 = AG + MROWS*256
    __half* AH = (__half*)(F + off);              off += (size_t)MROWS * 128;  // AH1
    __half* AH2 = (__half*)(F + off);             off += (size_t)MROWS * 128;  // AH2 (ping-pong)
    unsigned short* X240h = (unsigned short*)(F + off); off += (size_t)MROWS * 128;
    unsigned short* X240l = (unsigned short*)(F + off); off += (size_t)MROWS * 128;
    unsigned short* xc2h  = (unsigned short*)(F + off); off += (size_t)MROWS * 64;  // ld 128
    unsigned short* xc2l  = (unsigned short*)(F + off); off += (size_t)MROWS * 64;
    unsigned short* Wb2h = (unsigned short*)(F + off); off += 2048;
    unsigned short* Wb2l = (unsigned short*)(F + off); off += 2048;
    unsigned short* Wb3h = (unsigned short*)(F + off); off += 4096;
    unsigned short* Wb3l = (unsigned short*)(F + off); off += 4096;
    unsigned short* Wb4h = (unsigned short*)(F + off); off += 16384;
    unsigned short* Wb4l = (unsigned short*)(F + off); off += 16384;
    unsigned short* Wch  = (unsigned short*)(F + off); off += 24576;
    unsigned short* Wcl  = (unsigned short*)(F + off); off += 24576;
    unsigned short* Wi1h = (unsigned short*)(F + off); off += 32768;
    unsigned short* Wi1l = (unsigned short*)(F + off); off += 32768;
    unsigned short* Wi2h = (unsigned short*)(F + off); off += 32768;
    unsigned short* Wi2l = (unsigned short*)(F + off); off += 32768;
    float* part2 = F + off;                       off += (size_t)512 * 384;    // wc per-block sums
    float* ym    = F + off;                       off += 12 * 256;             // wi1 xm-part GEMM
    unsigned short* xmph = (unsigned short*)(F + off); off += 768;   // 12*128 u16
    unsigned short* xmpl = (unsigned short*)(F + off); off += 768;
    int* idx    = (int*)(F + off);                off += NBP * KNN_K;
    float* AG2 = AG + (size_t)MROWS * 256;

    // merged prep (layer-1 + weight builds) + knn
    prep_knn_kernel<<<KNN_BLOCKS + PREP_BLOCKS, 256, 0, stream>>>(
        x, idx, AH, AG, w1f, w1d,
        w2f, w2d, Wb2h, Wb2l, w3f, w3d, Wb3h, Wb3l, w4f, w4d, Wb4h, Wb4l,
        wcf, wcd, Wch, Wcl, wi1f, wi1d, Wi1h, Wi1l, wi2f, wi2d, Wi2h, Wi2l);

    // layer 1 edge + layer 2 gemm (fused): AH/AG (ld32) -> AH2/AG2 (ld64)
    edge_gemm_kernel<16, 2><<<NBP / 16, 256, 0, stream>>>(
        AH, AG, idx, X240h, X240l, 0, Wb2h, Wb2l, AH2, AG2);
    // layer 2 edge + layer 3 gemm (fused): AH2/AG2 (ld64) -> AH/AG (ld128)
    edge_gemm_kernel<32, 4><<<NBP / 16, 256, 0, stream>>>(
        AH2, AG2, idx, X240h, X240l, 16, Wb3h, Wb3l, AH, AG);
    // layer 3 edge + layer 4 gemm (fused): AH/AG (ld128) -> AH2/AG2 (ld256)
    edge_gemm4_kernel<<<NBP / 16, 256, 0, stream>>>(
        AH, AG, idx, X240h, X240l, Wb4h, Wb4l, AH2, AG2);

    // fused layer-4 edge + wc GEMM + lna -> xc2 + part2 (x4 never hits global)
    edge_wc_kernel<<<NBP / 16, 256, 0, stream>>>(AH2, AG2, idx, X240h, X240l,
                                                 Wch, Wcl, xc2h, xc2l, part2);

    // xm mean + ym precompute (single small dispatch)
    xm_reduce_ym_kernel<<<BATCH * 3, 128, 0, stream>>>(part2, xmph, xmpl, wi1f, wi1d, ym);

    // fused wi1 + wi2 + inv (y1 never hits global)
    gemm_ii_kernel<<<MROWS / 48, 256, 0, stream>>>(xc2h, xc2l, Wi1h, Wi1l,
                                                   Wi2h, Wi2l, xmph, xmpl, ym, out);

    (void)in_sizes; (void)n_in; (void)out_size; (void)ws_size;
}